// Round 2
// baseline (3280.433 us; speedup 1.0000x reference)
//
#include <hip/hip_runtime.h>
#include <cstddef>

typedef unsigned short u16;
typedef unsigned int   u32;

#define B_ROWS 16384
#define D_FEAT 512
#define NB_    8
#define E_     4
#define DT_    256

static __device__ __forceinline__ float b2f(u16 h) {
    union { u32 u; float f; } v; v.u = ((u32)h) << 16; return v.f;
}
static __device__ __forceinline__ u16 f2b(float f) {
    union { float f; u32 u; } v; v.f = f;
    u32 r = (v.u + 0x7fffu + ((v.u >> 16) & 1u)) >> 16;
    return (u16)r;
}
// load element i of an external tensor whose dtype is runtime-selected
static __device__ __forceinline__ float ldf(const void* p, size_t i, int isb) {
    return isb ? b2f(((const u16*)p)[i]) : ((const float*)p)[i];
}
static __device__ __forceinline__ float wred_sum(float v) {
    #pragma unroll
    for (int off = 32; off > 0; off >>= 1) v += __shfl_xor(v, off);
    return v;
}
static __device__ __forceinline__ float wred_max(float v) {
    #pragma unroll
    for (int off = 32; off > 0; off >>= 1) v = fmaxf(v, __shfl_xor(v, off));
    return v;
}

// ---------------- dtype detector: bf16 buffer -> even u16s are plausible bf16;
// fp32 buffer -> even u16s are mantissa noise (plausible ~6.6%) ----------------
__global__ void detect_k(const void* __restrict__ x, int* __restrict__ flag) {
    int lane = threadIdx.x & 63;
    u16 h = ((const u16*)x)[lane * 2];
    int e = (h >> 7) & 0xff;
    int plaus = (e >= 110 && e <= 132) ? 1 : 0;
    unsigned long long m = __ballot(plaus != 0);
    if (lane == 0) *flag = (__popcll(m) >= 32) ? 1 : 0;
}

// ---------------- K0: breakpoints: bps[d][k] = bp_min[d] + cumsum softplus(delta) ----
__global__ void prep_bps_k(const void* __restrict__ bp_min, const void* __restrict__ bp_dr,
                           float* __restrict__ bps, const int* __restrict__ flag) {
    const int isb = *flag;
    int d = threadIdx.x;
    if (d < D_FEAT) {
        float bp = ldf(bp_min, d, isb);
        #pragma unroll
        for (int k = 0; k < NB_; ++k) {
            float x = ldf(bp_dr, d * NB_ + k, isb);
            bp += fmaxf(x, 0.f) + log1pf(expf(-fabsf(x)));
            bps[d * NB_ + k] = bp;
        }
    }
}

// ---------------- generic fp32 GEMM: C = epilogue(A @ Bw + bias) ----------------
// AMODE: 0 = A from fp32 ws; 1 = A computed on-the-fly from GGPL embedding; 2 = A = x_in * g
// EMODE: 0 = x_in residual (xnum + 0.1*(z)); 1 = relu; 2 = sigmoid
template<int AMODE, int EMODE>
__global__ __launch_bounds__(256) void gemm_k(
    const float* __restrict__ A, const float* __restrict__ A2,
    const void* __restrict__ Bw, const void* __restrict__ bias,
    float* __restrict__ Cout,
    const void* __restrict__ xnum, const float* __restrict__ bps,
    const void* __restrict__ bwt, const void* __restrict__ bbias,
    int M, int N, int Kdim, const int* __restrict__ flag)
{
    __shared__ float As[32][68];
    __shared__ float Bs[32][64];
    __shared__ float xs[64][8];
    __shared__ float cw[8][36];
    __shared__ float cbps[8][8];
    __shared__ float cbias[8][4];

    const int isb = *flag;
    const int tid = threadIdx.x;
    const int row0 = blockIdx.x * 64, col0 = blockIdx.y * 64;
    const int tm = tid >> 4, tn = tid & 15;
    float acc[4][4] = {};

    for (int kt = 0; kt < Kdim; kt += 32) {
        // stage B tile 32 x 64 (dtype-branched scalar loads)
        {
            int kr = tid >> 3, nc = tid & 7;
            size_t base = (size_t)(kt + kr) * N + col0 + nc * 8;
            float* dst = &Bs[kr][nc * 8];
            #pragma unroll
            for (int j = 0; j < 8; ++j) dst[j] = ldf(Bw, base + j, isb);
        }
        if (AMODE == 1) {
            const int d0 = kt >> 2;  // 8 consecutive features per k-tile
            if (tid < 64) cbps[tid >> 3][tid & 7] = bps[(d0 + (tid >> 3)) * 8 + (tid & 7)];
            if (tid < 32) cbias[tid >> 2][tid & 3] = ldf(bbias, (d0 + (tid >> 2)) * 4 + (tid & 3), isb);
            for (int t = tid; t < 288; t += 256)
                cw[t / 36][t % 36] = ldf(bwt, (size_t)(d0 + t / 36) * 36 + (t % 36), isb);
            if (tid < 64) {
                #pragma unroll
                for (int j = 0; j < 8; ++j)
                    xs[tid][j] = ldf(xnum, (size_t)(row0 + tid) * D_FEAT + d0 + j, isb);
            }
            __syncthreads();
            for (int pp = tid; pp < 512; pp += 256) {
                int r = pp & 63, dl = pp >> 6;
                float x = xs[r][dl];
                float e0 = fmaf(x, cw[dl][0], cbias[dl][0]);
                float e1 = fmaf(x, cw[dl][1], cbias[dl][1]);
                float e2 = fmaf(x, cw[dl][2], cbias[dl][2]);
                float e3 = fmaf(x, cw[dl][3], cbias[dl][3]);
                #pragma unroll
                for (int f = 1; f <= 8; ++f) {
                    float bv = fmaxf(x - cbps[dl][f - 1], 0.f);
                    e0 = fmaf(bv, cw[dl][f * 4 + 0], e0);
                    e1 = fmaf(bv, cw[dl][f * 4 + 1], e1);
                    e2 = fmaf(bv, cw[dl][f * 4 + 2], e2);
                    e3 = fmaf(bv, cw[dl][f * 4 + 3], e3);
                }
                As[dl * 4 + 0][r] = e0; As[dl * 4 + 1][r] = e1;
                As[dl * 4 + 2][r] = e2; As[dl * 4 + 3][r] = e3;
            }
        } else {
            #pragma unroll
            for (int i = 0; i < 2; ++i) {
                int id = tid + i * 256;
                int r = id >> 3, c = id & 7;
                const float* pa = A + (size_t)(row0 + r) * Kdim + kt + c * 4;
                float4 v = *(const float4*)pa;
                if (AMODE == 2) {
                    const float* pg = A2 + (size_t)(row0 + r) * Kdim + kt + c * 4;
                    float4 gq = *(const float4*)pg;
                    v.x *= gq.x; v.y *= gq.y; v.z *= gq.z; v.w *= gq.w;
                }
                As[c * 4 + 0][r] = v.x; As[c * 4 + 1][r] = v.y;
                As[c * 4 + 2][r] = v.z; As[c * 4 + 3][r] = v.w;
            }
        }
        __syncthreads();
        #pragma unroll 8
        for (int kk = 0; kk < 32; ++kk) {
            float4 a4 = *(const float4*)&As[kk][tm * 4];
            float4 b4 = *(const float4*)&Bs[kk][tn * 4];
            float av[4] = {a4.x, a4.y, a4.z, a4.w};
            float bv[4] = {b4.x, b4.y, b4.z, b4.w};
            #pragma unroll
            for (int i = 0; i < 4; ++i)
                #pragma unroll
                for (int j = 0; j < 4; ++j)
                    acc[i][j] = fmaf(av[i], bv[j], acc[i][j]);
        }
        __syncthreads();
    }
    #pragma unroll
    for (int i = 0; i < 4; ++i) {
        size_t r = row0 + tm * 4 + i;
        int cbase = col0 + tn * 4;
        float vv[4];
        #pragma unroll
        for (int j = 0; j < 4; ++j) {
            int c = cbase + j;
            float z = acc[i][j] + ldf(bias, c, isb);
            if (EMODE == 0)      z = ldf(xnum, r * (size_t)N + c, isb) + 0.1f * z;
            else if (EMODE == 1) z = fmaxf(z, 0.f);
            else                 z = 1.f / (1.f + expf(-z));
            vv[j] = z;
        }
        float4 o; o.x = vv[0]; o.y = vv[1]; o.z = vv[2]; o.w = vv[3];
        *(float4*)&Cout[r * (size_t)N + cbase] = o;
    }
}

// ---------------- K4: per-row heads (one wave per row) ----------------
struct HeadArgs {
    const float *x_in, *g, *h;
    const void *base_W, *base_b;
    const void *safe_ln_g, *safe_ln_b, *safe_W1, *safe_b1, *safe_W2, *safe_b2;
    const void *top_W1, *top_b1, *top_W2, *top_b2;
    const void *spec_ln_g, *spec_ln_b, *spec_W1, *spec_b1, *spec_W2, *spec_b2;
    const void *conf_ln_g, *conf_ln_b, *conf_W1, *conf_b1, *conf_W2, *conf_b2;
    void *out;
    const int *flag;
};

__global__ __launch_bounds__(256) void heads_k(HeadArgs P) {
    __shared__ float lbuf[4][280];
    __shared__ float zb[4][16];
    const int isb = *P.flag;
    const int wid = threadIdx.x >> 6;
    const int lane = threadIdx.x & 63;
    const int row = blockIdx.x * 4 + wid;

    float hv[4], gv[8];
    #pragma unroll
    for (int i = 0; i < 4; ++i) hv[i] = P.h[(size_t)row * 256 + lane + 64 * i];
    #pragma unroll
    for (int j = 0; j < 8; ++j) gv[j] = P.g[(size_t)row * 512 + lane + 64 * j];
    const float hsum = hv[0] + hv[1] + hv[2] + hv[3];

    // y_base
    float pb = 0.f;
    #pragma unroll
    for (int i = 0; i < 4; ++i) pb = fmaf(hv[i], ldf(P.base_W, lane + 64 * i, isb), pb);
    const float yb = wred_sum(pb) + ldf(P.base_b, 0, isb);

    // gate stats (population std)
    float s1 = 0.f, s2 = 0.f, mx = -1e30f;
    #pragma unroll
    for (int j = 0; j < 8; ++j) { s1 += gv[j]; s2 = fmaf(gv[j], gv[j], s2); mx = fmaxf(mx, gv[j]); }
    s1 = wred_sum(s1); s2 = wred_sum(s2); mx = wred_max(mx);
    const float gmean = s1 * (1.f / 512.f);
    const float gstd = sqrtf(fmaxf(s2 * (1.f / 512.f) - gmean * gmean, 0.f));

    // ---- safe head: LN(h) -> 128 hidden -> scalar ----
    const float hm = wred_sum(hsum) * (1.f / 256.f);
    float pv = 0.f;
    #pragma unroll
    for (int i = 0; i < 4; ++i) { float d = hv[i] - hm; pv = fmaf(d, d, pv); }
    const float hrstd = rsqrtf(wred_sum(pv) * (1.f / 256.f) + 1e-5f);
    #pragma unroll
    for (int i = 0; i < 4; ++i) {
        int k = lane + 64 * i;
        lbuf[wid][k] = (hv[i] - hm) * hrstd * ldf(P.safe_ln_g, k, isb) + ldf(P.safe_ln_b, k, isb);
    }
    __syncthreads();
    float sa0 = ldf(P.safe_b1, lane, isb);
    float sa1 = ldf(P.safe_b1, 64 + lane, isb);
    for (int k = 0; k < 256; ++k) {
        float xk = lbuf[wid][k];
        sa0 = fmaf(xk, ldf(P.safe_W1, (size_t)k * 128 + lane, isb), sa0);
        sa1 = fmaf(xk, ldf(P.safe_W1, (size_t)k * 128 + 64 + lane, isb), sa1);
    }
    float psafe = fmaxf(sa0, 0.f) * ldf(P.safe_W2, lane, isb)
                + fmaxf(sa1, 0.f) * ldf(P.safe_W2, 64 + lane, isb);
    const float dsafe = wred_sum(psafe) + ldf(P.safe_b2, 0, isb);

    // ---- top-k (K=8), jax tie semantics: desc value, asc index ----
    float tg[8];
    #pragma unroll
    for (int j = 0; j < 8; ++j) tg[j] = gv[j];
    float myv = 0.f, sumtv = 0.f; int myi = 0;
    for (int r8 = 0; r8 < 8; ++r8) {
        float bv = -1e30f; int bi = 0x7fffffff;
        #pragma unroll
        for (int j = 0; j < 8; ++j) {
            int idx = lane + 64 * j;
            if (tg[j] > bv || (tg[j] == bv && idx < bi)) { bv = tg[j]; bi = idx; }
        }
        #pragma unroll
        for (int off = 32; off > 0; off >>= 1) {
            float ov = __shfl_xor(bv, off);
            int oi = __shfl_xor(bi, off);
            if (ov > bv || (ov == bv && oi < bi)) { bv = ov; bi = oi; }
        }
        sumtv += bv;
        if (lane == r8) { myv = bv; myi = bi; }
        if ((bi & 63) == lane) {
            int oj = bi >> 6;
            #pragma unroll
            for (int j = 0; j < 8; ++j) if (j == oj) tg[j] = -1e30f;
        }
    }

    // ---- token MLP + mean over K -> z_top[16] ----
    float zt[16];
    #pragma unroll
    for (int t = 0; t < 16; ++t) zt[t] = 0.f;
    if (lane < 8) {
        float xi = P.x_in[(size_t)row * 512 + myi];
        float xw = xi * (myv / (sumtv + 1e-6f));
        float th[16];
        #pragma unroll
        for (int s = 0; s < 16; ++s)
            th[s] = fmaxf(fmaf(xw, ldf(P.top_W1, s, isb), ldf(P.top_b1, s, isb)), 0.f);
        #pragma unroll
        for (int t = 0; t < 16; ++t) {
            float o = ldf(P.top_b2, t, isb);
            #pragma unroll
            for (int s = 0; s < 16; ++s) o = fmaf(th[s], ldf(P.top_W2, s * 16 + t, isb), o);
            zt[t] = o;
        }
    }
    #pragma unroll
    for (int t = 0; t < 16; ++t) {
        zt[t] += __shfl_xor(zt[t], 1);
        zt[t] += __shfl_xor(zt[t], 2);
        zt[t] += __shfl_xor(zt[t], 4);
    }
    if (lane == 0) {
        #pragma unroll
        for (int t = 0; t < 16; ++t) zb[wid][t] = zt[t] * 0.125f;
    }
    __syncthreads();
    const float ztl = (lane < 16) ? zb[wid][lane] : 0.f;

    // ---- spec head: LN([h, z_top]) (272) -> 68 -> scalar ----
    float ps = hsum + ((lane < 16) ? ztl : 0.f);
    const float sm = wred_sum(ps) * (1.f / 272.f);
    float pv2 = 0.f;
    #pragma unroll
    for (int i = 0; i < 4; ++i) { float d = hv[i] - sm; pv2 = fmaf(d, d, pv2); }
    if (lane < 16) { float d = ztl - sm; pv2 = fmaf(d, d, pv2); }
    const float srstd = rsqrtf(wred_sum(pv2) * (1.f / 272.f) + 1e-5f);
    #pragma unroll
    for (int i = 0; i < 4; ++i) {
        int k = lane + 64 * i;
        lbuf[wid][k] = (hv[i] - sm) * srstd * ldf(P.spec_ln_g, k, isb) + ldf(P.spec_ln_b, k, isb);
    }
    if (lane < 16) {
        int k = 256 + lane;
        lbuf[wid][k] = (ztl - sm) * srstd * ldf(P.spec_ln_g, k, isb) + ldf(P.spec_ln_b, k, isb);
    }
    __syncthreads();
    const int sc1 = 64 + (lane & 3);
    float sb0 = ldf(P.spec_b1, lane, isb);
    float sb1 = ldf(P.spec_b1, sc1, isb);
    for (int k = 0; k < 272; ++k) {
        float xk = lbuf[wid][k];
        sb0 = fmaf(xk, ldf(P.spec_W1, (size_t)k * 68 + lane, isb), sb0);
        sb1 = fmaf(xk, ldf(P.spec_W1, (size_t)k * 68 + sc1, isb), sb1);
    }
    float pspec = fmaxf(sb0, 0.f) * ldf(P.spec_W2, lane, isb)
                + ((lane < 4) ? fmaxf(sb1, 0.f) * ldf(P.spec_W2, sc1, isb) : 0.f);
    const float dspec = wred_sum(pspec) + ldf(P.spec_b2, 0, isb);
    __syncthreads();

    // ---- conf gate: LN([h, yb, gmean, gmax, gstd, z_top, |ds|, |dsp|]) (278) -> 69 -> sigmoid ----
    const float ads = fabsf(dsafe), adsp = fabsf(dspec);
    float pc = hsum + ((lane < 16) ? ztl : 0.f)
             + ((lane == 0) ? (yb + gmean + mx + gstd + ads + adsp) : 0.f);
    const float cm = wred_sum(pc) * (1.f / 278.f);
    float pv3 = 0.f;
    #pragma unroll
    for (int i = 0; i < 4; ++i) { float d = hv[i] - cm; pv3 = fmaf(d, d, pv3); }
    if (lane < 16) { float d = ztl - cm; pv3 = fmaf(d, d, pv3); }
    if (lane == 0) {
        float vals[6] = { yb, gmean, mx, gstd, ads, adsp };
        #pragma unroll
        for (int q = 0; q < 6; ++q) { float d = vals[q] - cm; pv3 = fmaf(d, d, pv3); }
    }
    const float crstd = rsqrtf(wred_sum(pv3) * (1.f / 278.f) + 1e-5f);
    #pragma unroll
    for (int i = 0; i < 4; ++i) {
        int k = lane + 64 * i;
        lbuf[wid][k] = (hv[i] - cm) * crstd * ldf(P.conf_ln_g, k, isb) + ldf(P.conf_ln_b, k, isb);
    }
    if (lane < 16) {
        int k = 260 + lane;
        lbuf[wid][k] = (ztl - cm) * crstd * ldf(P.conf_ln_g, k, isb) + ldf(P.conf_ln_b, k, isb);
    }
    if (lane == 0) {
        float vals[6] = { yb, gmean, mx, gstd, ads, adsp };
        int idxs[6] = { 256, 257, 258, 259, 276, 277 };
        #pragma unroll
        for (int q = 0; q < 6; ++q) {
            int k = idxs[q];
            lbuf[wid][k] = (vals[q] - cm) * crstd * ldf(P.conf_ln_g, k, isb) + ldf(P.conf_ln_b, k, isb);
        }
    }
    __syncthreads();
    const int cc1 = 64 + (lane % 5);
    float ca0 = ldf(P.conf_b1, lane, isb);
    float ca1 = ldf(P.conf_b1, cc1, isb);
    for (int k = 0; k < 278; ++k) {
        float xk = lbuf[wid][k];
        ca0 = fmaf(xk, ldf(P.conf_W1, (size_t)k * 69 + lane, isb), ca0);
        ca1 = fmaf(xk, ldf(P.conf_W1, (size_t)k * 69 + cc1, isb), ca1);
    }
    float pconf = fmaxf(ca0, 0.f) * ldf(P.conf_W2, lane, isb)
                + ((lane < 5) ? fmaxf(ca1, 0.f) * ldf(P.conf_W2, cc1, isb) : 0.f);
    const float zlin = wred_sum(pconf) + ldf(P.conf_b2, 0, isb);
    const float gamma = 1.f / (1.f + expf(-zlin));
    if (lane == 0) {
        float v = yb + dsafe + gamma * dspec;
        if (isb) ((u16*)P.out)[row] = f2b(v);
        else     ((float*)P.out)[row] = v;
    }
}

extern "C" void kernel_launch(void* const* d_in, const int* in_sizes, int n_in,
                              void* d_out, int out_size, void* d_ws, size_t ws_size,
                              hipStream_t stream) {
    (void)in_sizes; (void)n_in; (void)out_size; (void)ws_size;
    const void* x_num        = d_in[0];
    const void* basis_weight = d_in[1];
    const void* basis_bias   = d_in[2];
    const void* bp_min       = d_in[3];
    const void* bp_delta     = d_in[4];
    const void* proj_W       = d_in[5];
    const void* proj_b       = d_in[6];
    const void* gate_W1      = d_in[7];
    const void* gate_b1      = d_in[8];
    const void* gate_W2      = d_in[9];
    const void* gate_b2      = d_in[10];
    const void* bb_W1        = d_in[11];
    const void* bb_b1        = d_in[12];
    const void* bb_W2        = d_in[13];
    const void* bb_b2        = d_in[14];

    float* ws   = (float*)d_ws;
    int*  flag  = (int*)d_ws;                            // 1 int (slot of 16 floats)
    float* bps  = ws + 16;                               // 4096
    float* x_in = bps + 4096;                            // B*512
    float* gbuf = x_in + (size_t)B_ROWS * D_FEAT;        // B*512
    float* hid  = gbuf + (size_t)B_ROWS * D_FEAT;        // B*256 (gate hidden, then bb hidden)
    float* hbuf = hid  + (size_t)B_ROWS * DT_;           // B*256

    detect_k<<<1, 64, 0, stream>>>(x_num, flag);
    prep_bps_k<<<1, 512, 0, stream>>>(bp_min, bp_delta, bps, flag);

    // x_in = x_num + 0.1*(flat @ proj_W + proj_b)   [embed fused into A-staging]
    gemm_k<1, 0><<<dim3(B_ROWS / 64, 512 / 64), 256, 0, stream>>>(
        nullptr, nullptr, proj_W, proj_b, x_in,
        x_num, bps, basis_weight, basis_bias, B_ROWS, 512, 2048, flag);

    // gate hidden = relu(x_in @ gate_W1 + b1)
    gemm_k<0, 1><<<dim3(B_ROWS / 64, 256 / 64), 256, 0, stream>>>(
        x_in, nullptr, gate_W1, gate_b1, hid,
        nullptr, nullptr, nullptr, nullptr, B_ROWS, 256, 512, flag);

    // g = sigmoid(hidden @ gate_W2 + b2)
    gemm_k<0, 2><<<dim3(B_ROWS / 64, 512 / 64), 256, 0, stream>>>(
        hid, nullptr, gate_W2, gate_b2, gbuf,
        nullptr, nullptr, nullptr, nullptr, B_ROWS, 512, 256, flag);

    // bb hidden = relu((x_in * g) @ bb_W1 + b1)
    gemm_k<2, 1><<<dim3(B_ROWS / 64, 256 / 64), 256, 0, stream>>>(
        x_in, gbuf, bb_W1, bb_b1, hid,
        nullptr, nullptr, nullptr, nullptr, B_ROWS, 256, 512, flag);

    // h = relu(hidden @ bb_W2 + b2)
    gemm_k<0, 1><<<dim3(B_ROWS / 64, 256 / 64), 256, 0, stream>>>(
        hid, nullptr, bb_W2, bb_b2, hbuf,
        nullptr, nullptr, nullptr, nullptr, B_ROWS, 256, 256, flag);

    HeadArgs ha;
    ha.x_in = x_in; ha.g = gbuf; ha.h = hbuf;
    ha.base_W    = d_in[15]; ha.base_b    = d_in[16];
    ha.safe_ln_g = d_in[17]; ha.safe_ln_b = d_in[18];
    ha.safe_W1   = d_in[19]; ha.safe_b1   = d_in[20];
    ha.safe_W2   = d_in[21]; ha.safe_b2   = d_in[22];
    ha.top_W1    = d_in[23]; ha.top_b1    = d_in[24];
    ha.top_W2    = d_in[25]; ha.top_b2    = d_in[26];
    ha.spec_ln_g = d_in[27]; ha.spec_ln_b = d_in[28];
    ha.spec_W1   = d_in[29]; ha.spec_b1   = d_in[30];
    ha.spec_W2   = d_in[31]; ha.spec_b2   = d_in[32];
    ha.conf_ln_g = d_in[33]; ha.conf_ln_b = d_in[34];
    ha.conf_W1   = d_in[35]; ha.conf_b1   = d_in[36];
    ha.conf_W2   = d_in[37]; ha.conf_b2   = d_in[38];
    ha.out = d_out;
    ha.flag = flag;

    heads_k<<<B_ROWS / 4, 256, 0, stream>>>(ha);
}

// Round 3
// 1914.404 us; speedup vs baseline: 1.7136x; 1.7136x over previous
//
#include <hip/hip_runtime.h>
#include <cstddef>

typedef unsigned short u16;
typedef unsigned int   u32;

#define B_ROWS 16384
#define D_FEAT 512
#define NB_    8
#define DT_    256

static __device__ __forceinline__ float b2f(u16 h) {
    union { u32 u; float f; } v; v.u = ((u32)h) << 16; return v.f;
}
static __device__ __forceinline__ u16 f2b(float f) {
    union { float f; u32 u; } v; v.f = f;
    u32 r = (v.u + 0x7fffu + ((v.u >> 16) & 1u)) >> 16;
    return (u16)r;
}
static __device__ __forceinline__ float ldf(const void* p, size_t i, int isb) {
    return isb ? b2f(((const u16*)p)[i]) : ((const float*)p)[i];
}
static __device__ __forceinline__ float wred_sum(float v) {
    #pragma unroll
    for (int off = 32; off > 0; off >>= 1) v += __shfl_xor(v, off);
    return v;
}
static __device__ __forceinline__ float wred_max(float v) {
    #pragma unroll
    for (int off = 32; off > 0; off >>= 1) v = fmaxf(v, __shfl_xor(v, off));
    return v;
}

// ---------------- dtype detector ----------------
__global__ void detect_k(const void* __restrict__ x, int* __restrict__ flag) {
    int lane = threadIdx.x & 63;
    u16 h = ((const u16*)x)[lane * 2];
    int e = (h >> 7) & 0xff;
    int plaus = (e >= 110 && e <= 132) ? 1 : 0;
    unsigned long long m = __ballot(plaus != 0);
    if (lane == 0) *flag = (__popcll(m) >= 32) ? 1 : 0;
}

// ---------------- K0: breakpoints ----------------
__global__ void prep_bps_k(const void* __restrict__ bp_min, const void* __restrict__ bp_dr,
                           float* __restrict__ bps, const int* __restrict__ flag) {
    const int isb = *flag;
    int d = threadIdx.x;
    if (d < D_FEAT) {
        float bp = ldf(bp_min, d, isb);
        #pragma unroll
        for (int k = 0; k < NB_; ++k) {
            float x = ldf(bp_dr, d * NB_ + k, isb);
            bp += fmaxf(x, 0.f) + log1pf(expf(-fabsf(x)));
            bps[d * NB_ + k] = bp;
        }
    }
}

// ---------------- repack spec/conf W1,b1 into zero-padded fp32 [288 x 128] ----
__global__ void repack_k(const void* sW1, const void* sb1, const void* cW1, const void* cb1,
                         float* sW1p, float* sb1p, float* cW1p, float* cb1p,
                         const int* __restrict__ flag) {
    const int isb = *flag;
    int t = blockIdx.x * 256 + threadIdx.x;
    if (t < 288 * 128) {
        int r = t >> 7, c = t & 127;
        sW1p[t] = (r < 272 && c < 68) ? ldf(sW1, (size_t)r * 68 + c, isb) : 0.f;
        cW1p[t] = (r < 278 && c < 69) ? ldf(cW1, (size_t)r * 69 + c, isb) : 0.f;
    }
    if (t < 128) {
        sb1p[t] = (t < 68) ? ldf(sb1, t, isb) : 0.f;
        cb1p[t] = (t < 69) ? ldf(cb1, t, isb) : 0.f;
    }
}

// ---------------- generic fp32 GEMM: C = epilogue(A @ Bw + bias) ----------------
// AMODE: 0 = A from fp32 ws; 1 = GGPL embedding on-the-fly; 2 = A = x_in * g
// EMODE: 0 = residual; 1 = relu; 2 = sigmoid.  BFP32: Bw/bias are fp32 (ignore flag)
template<int AMODE, int EMODE, int BFP32>
__global__ __launch_bounds__(256) void gemm_k(
    const float* __restrict__ A, const float* __restrict__ A2,
    const void* __restrict__ Bw, const void* __restrict__ bias,
    float* __restrict__ Cout,
    const void* __restrict__ xnum, const float* __restrict__ bps,
    const void* __restrict__ bwt, const void* __restrict__ bbias,
    int M, int N, int Kdim, int lda, const int* __restrict__ flag)
{
    __shared__ float As[32][68];
    __shared__ float Bs[32][64];
    __shared__ float xs[64][8];
    __shared__ float cw[8][36];
    __shared__ float cbps[8][8];
    __shared__ float cbias[8][4];

    const int isb = *flag;
    const int tid = threadIdx.x;
    const int row0 = blockIdx.x * 64, col0 = blockIdx.y * 64;
    const int tm = tid >> 4, tn = tid & 15;
    float acc[4][4] = {};

    for (int kt = 0; kt < Kdim; kt += 32) {
        {
            int kr = tid >> 3, nc = tid & 7;
            size_t base = (size_t)(kt + kr) * N + col0 + nc * 8;
            float* dst = &Bs[kr][nc * 8];
            #pragma unroll
            for (int j = 0; j < 8; ++j)
                dst[j] = BFP32 ? ((const float*)Bw)[base + j] : ldf(Bw, base + j, isb);
        }
        if (AMODE == 1) {
            const int d0 = kt >> 2;
            if (tid < 64) cbps[tid >> 3][tid & 7] = bps[(d0 + (tid >> 3)) * 8 + (tid & 7)];
            if (tid < 32) cbias[tid >> 2][tid & 3] = ldf(bbias, (d0 + (tid >> 2)) * 4 + (tid & 3), isb);
            for (int t = tid; t < 288; t += 256)
                cw[t / 36][t % 36] = ldf(bwt, (size_t)(d0 + t / 36) * 36 + (t % 36), isb);
            if (tid < 64) {
                #pragma unroll
                for (int j = 0; j < 8; ++j)
                    xs[tid][j] = ldf(xnum, (size_t)(row0 + tid) * D_FEAT + d0 + j, isb);
            }
            __syncthreads();
            for (int pp = tid; pp < 512; pp += 256) {
                int r = pp & 63, dl = pp >> 6;
                float x = xs[r][dl];
                float e0 = fmaf(x, cw[dl][0], cbias[dl][0]);
                float e1 = fmaf(x, cw[dl][1], cbias[dl][1]);
                float e2 = fmaf(x, cw[dl][2], cbias[dl][2]);
                float e3 = fmaf(x, cw[dl][3], cbias[dl][3]);
                #pragma unroll
                for (int f = 1; f <= 8; ++f) {
                    float bv = fmaxf(x - cbps[dl][f - 1], 0.f);
                    e0 = fmaf(bv, cw[dl][f * 4 + 0], e0);
                    e1 = fmaf(bv, cw[dl][f * 4 + 1], e1);
                    e2 = fmaf(bv, cw[dl][f * 4 + 2], e2);
                    e3 = fmaf(bv, cw[dl][f * 4 + 3], e3);
                }
                As[dl * 4 + 0][r] = e0; As[dl * 4 + 1][r] = e1;
                As[dl * 4 + 2][r] = e2; As[dl * 4 + 3][r] = e3;
            }
        } else {
            #pragma unroll
            for (int i = 0; i < 2; ++i) {
                int id = tid + i * 256;
                int r = id >> 3, c = id & 7;
                const float* pa = A + (size_t)(row0 + r) * lda + kt + c * 4;
                float4 v = *(const float4*)pa;
                if (AMODE == 2) {
                    const float* pg = A2 + (size_t)(row0 + r) * lda + kt + c * 4;
                    float4 gq = *(const float4*)pg;
                    v.x *= gq.x; v.y *= gq.y; v.z *= gq.z; v.w *= gq.w;
                }
                As[c * 4 + 0][r] = v.x; As[c * 4 + 1][r] = v.y;
                As[c * 4 + 2][r] = v.z; As[c * 4 + 3][r] = v.w;
            }
        }
        __syncthreads();
        #pragma unroll 8
        for (int kk = 0; kk < 32; ++kk) {
            float4 a4 = *(const float4*)&As[kk][tm * 4];
            float4 b4 = *(const float4*)&Bs[kk][tn * 4];
            float av[4] = {a4.x, a4.y, a4.z, a4.w};
            float bv[4] = {b4.x, b4.y, b4.z, b4.w};
            #pragma unroll
            for (int i = 0; i < 4; ++i)
                #pragma unroll
                for (int j = 0; j < 4; ++j)
                    acc[i][j] = fmaf(av[i], bv[j], acc[i][j]);
        }
        __syncthreads();
    }
    #pragma unroll
    for (int i = 0; i < 4; ++i) {
        size_t r = row0 + tm * 4 + i;
        int cbase = col0 + tn * 4;
        float vv[4];
        #pragma unroll
        for (int j = 0; j < 4; ++j) {
            int c = cbase + j;
            float z = acc[i][j] + (BFP32 ? ((const float*)bias)[c] : ldf(bias, c, isb));
            if (EMODE == 0)      z = ldf(xnum, r * (size_t)N + c, isb) + 0.1f * z;
            else if (EMODE == 1) z = fmaxf(z, 0.f);
            else                 z = 1.f / (1.f + expf(-z));
            vv[j] = z;
        }
        float4 o; o.x = vv[0]; o.y = vv[1]; o.z = vv[2]; o.w = vv[3];
        *(float4*)&Cout[r * (size_t)N + cbase] = o;
    }
}

// ---------------- pre_k: per-row stats, top-k, z_top, safe-LN, spec-LN ----------------
struct PreArgs {
    const float *x_in, *g, *h;
    const void *base_W, *base_b;
    const void *safe_ln_g, *safe_ln_b;
    const void *top_W1, *top_b1, *top_W2, *top_b2;
    const void *spec_ln_g, *spec_ln_b;
    float *ln_a, *ln_b, *scal;
    const int *flag;
};

__global__ __launch_bounds__(256) void pre_k(PreArgs P) {
    __shared__ float zbs[4][16];
    const int isb = *P.flag;
    const int wid = threadIdx.x >> 6;
    const int lane = threadIdx.x & 63;
    const int row = blockIdx.x * 4 + wid;

    float hv[4], gv[8];
    #pragma unroll
    for (int i = 0; i < 4; ++i) hv[i] = P.h[(size_t)row * 256 + lane + 64 * i];
    #pragma unroll
    for (int j = 0; j < 8; ++j) gv[j] = P.g[(size_t)row * 512 + lane + 64 * j];
    const float hsum = hv[0] + hv[1] + hv[2] + hv[3];

    // y_base
    float pb = 0.f;
    #pragma unroll
    for (int i = 0; i < 4; ++i) pb = fmaf(hv[i], ldf(P.base_W, lane + 64 * i, isb), pb);
    const float yb = wred_sum(pb) + ldf(P.base_b, 0, isb);

    // gate stats
    float s1 = 0.f, s2 = 0.f, mx = -1e30f;
    #pragma unroll
    for (int j = 0; j < 8; ++j) { s1 += gv[j]; s2 = fmaf(gv[j], gv[j], s2); mx = fmaxf(mx, gv[j]); }
    s1 = wred_sum(s1); s2 = wred_sum(s2); mx = wred_max(mx);
    const float gmean = s1 * (1.f / 512.f);
    const float gstd = sqrtf(fmaxf(s2 * (1.f / 512.f) - gmean * gmean, 0.f));

    // safe LN -> ln_a[row][0..255]
    const float hm = wred_sum(hsum) * (1.f / 256.f);
    float pv = 0.f;
    #pragma unroll
    for (int i = 0; i < 4; ++i) { float d = hv[i] - hm; pv = fmaf(d, d, pv); }
    const float hrstd = rsqrtf(wred_sum(pv) * (1.f / 256.f) + 1e-5f);
    #pragma unroll
    for (int i = 0; i < 4; ++i) {
        int k = lane + 64 * i;
        P.ln_a[(size_t)row * 288 + k] =
            (hv[i] - hm) * hrstd * ldf(P.safe_ln_g, k, isb) + ldf(P.safe_ln_b, k, isb);
    }

    // top-k (K=8), desc value / asc index ties
    float tg[8];
    #pragma unroll
    for (int j = 0; j < 8; ++j) tg[j] = gv[j];
    float myv = 0.f, sumtv = 0.f; int myi = 0;
    for (int r8 = 0; r8 < 8; ++r8) {
        float bv = -1e30f; int bi = 0x7fffffff;
        #pragma unroll
        for (int j = 0; j < 8; ++j) {
            int idx = lane + 64 * j;
            if (tg[j] > bv || (tg[j] == bv && idx < bi)) { bv = tg[j]; bi = idx; }
        }
        #pragma unroll
        for (int off = 32; off > 0; off >>= 1) {
            float ov = __shfl_xor(bv, off);
            int oi = __shfl_xor(bi, off);
            if (ov > bv || (ov == bv && oi < bi)) { bv = ov; bi = oi; }
        }
        sumtv += bv;
        if (lane == r8) { myv = bv; myi = bi; }
        if ((bi & 63) == lane) {
            int oj = bi >> 6;
            #pragma unroll
            for (int j = 0; j < 8; ++j) if (j == oj) tg[j] = -1e30f;
        }
    }

    // token MLP + mean -> z_top[16]
    float zt[16];
    #pragma unroll
    for (int t = 0; t < 16; ++t) zt[t] = 0.f;
    if (lane < 8) {
        float xi = P.x_in[(size_t)row * 512 + myi];
        float xw = xi * (myv / (sumtv + 1e-6f));
        float th[16];
        #pragma unroll
        for (int s = 0; s < 16; ++s)
            th[s] = fmaxf(fmaf(xw, ldf(P.top_W1, s, isb), ldf(P.top_b1, s, isb)), 0.f);
        #pragma unroll
        for (int t = 0; t < 16; ++t) {
            float o = ldf(P.top_b2, t, isb);
            #pragma unroll
            for (int s = 0; s < 16; ++s) o = fmaf(th[s], ldf(P.top_W2, s * 16 + t, isb), o);
            zt[t] = o;
        }
    }
    #pragma unroll
    for (int t = 0; t < 16; ++t) {
        zt[t] += __shfl_xor(zt[t], 1);
        zt[t] += __shfl_xor(zt[t], 2);
        zt[t] += __shfl_xor(zt[t], 4);
    }
    if (lane == 0) {
        #pragma unroll
        for (int t = 0; t < 16; ++t) zbs[wid][t] = zt[t] * 0.125f;
    }
    __syncthreads();
    const float ztl = (lane < 16) ? zbs[wid][lane] : 0.f;

    // spec LN over [h(256), z_top(16)] -> ln_b[row][0..271], zeros 272..287
    float ps = hsum + ((lane < 16) ? ztl : 0.f);
    const float sm = wred_sum(ps) * (1.f / 272.f);
    float pv2 = 0.f;
    #pragma unroll
    for (int i = 0; i < 4; ++i) { float d = hv[i] - sm; pv2 = fmaf(d, d, pv2); }
    if (lane < 16) { float d = ztl - sm; pv2 = fmaf(d, d, pv2); }
    const float srstd = rsqrtf(wred_sum(pv2) * (1.f / 272.f) + 1e-5f);
    #pragma unroll
    for (int i = 0; i < 4; ++i) {
        int k = lane + 64 * i;
        P.ln_b[(size_t)row * 288 + k] =
            (hv[i] - sm) * srstd * ldf(P.spec_ln_g, k, isb) + ldf(P.spec_ln_b, k, isb);
    }
    if (lane < 16) {
        int k = 256 + lane;
        P.ln_b[(size_t)row * 288 + k] =
            (ztl - sm) * srstd * ldf(P.spec_ln_g, k, isb) + ldf(P.spec_ln_b, k, isb);
    } else if (lane < 32) {
        P.ln_b[(size_t)row * 288 + 256 + lane] = 0.f;
    }

    if (lane == 0) {
        float* sc = P.scal + (size_t)row * 32;
        sc[0] = yb; sc[1] = gmean; sc[2] = mx; sc[3] = gstd;
        #pragma unroll
        for (int t = 0; t < 16; ++t) sc[8 + t] = zbs[wid][t];
    }
}

// ---------------- mid_k: dsafe/dspec + conf-LN ----------------
struct MidArgs {
    const float *h, *sh, *sph, *scal_in;
    const void *safe_W2, *safe_b2, *spec_W2, *spec_b2;
    const void *conf_ln_g, *conf_ln_b;
    float *ln_a, *scal;
    const int *flag;
};

__global__ __launch_bounds__(256) void mid_k(MidArgs P) {
    const int isb = *P.flag;
    const int wid = threadIdx.x >> 6;
    const int lane = threadIdx.x & 63;
    const int row = blockIdx.x * 4 + wid;

    // dsafe: sh already relu'd, 128 wide
    float s0 = P.sh[(size_t)row * 128 + lane];
    float s1 = P.sh[(size_t)row * 128 + 64 + lane];
    float psafe = s0 * ldf(P.safe_W2, lane, isb) + s1 * ldf(P.safe_W2, 64 + lane, isb);
    const float dsafe = wred_sum(psafe) + ldf(P.safe_b2, 0, isb);

    // dspec: sph relu'd, 68 wide (stride 128)
    float p0 = P.sph[(size_t)row * 128 + lane] * ldf(P.spec_W2, lane, isb);
    if (lane < 4) p0 += P.sph[(size_t)row * 128 + 64 + lane] * ldf(P.spec_W2, 64 + lane, isb);
    const float dspec = wred_sum(p0) + ldf(P.spec_b2, 0, isb);

    const float* sc = P.scal_in + (size_t)row * 32;
    const float yb = sc[0], gmean = sc[1], mx = sc[2], gstd = sc[3];
    const float ztl = (lane < 16) ? sc[8 + lane] : 0.f;

    float hv[4];
    #pragma unroll
    for (int i = 0; i < 4; ++i) hv[i] = P.h[(size_t)row * 256 + lane + 64 * i];
    const float hsum = hv[0] + hv[1] + hv[2] + hv[3];

    const float ads = fabsf(dsafe), adsp = fabsf(dspec);
    float pc = hsum + ((lane < 16) ? ztl : 0.f)
             + ((lane == 0) ? (yb + gmean + mx + gstd + ads + adsp) : 0.f);
    const float cm = wred_sum(pc) * (1.f / 278.f);
    float pv3 = 0.f;
    #pragma unroll
    for (int i = 0; i < 4; ++i) { float d = hv[i] - cm; pv3 = fmaf(d, d, pv3); }
    if (lane < 16) { float d = ztl - cm; pv3 = fmaf(d, d, pv3); }
    if (lane == 0) {
        float vals[6] = { yb, gmean, mx, gstd, ads, adsp };
        #pragma unroll
        for (int q = 0; q < 6; ++q) { float d = vals[q] - cm; pv3 = fmaf(d, d, pv3); }
    }
    const float crstd = rsqrtf(wred_sum(pv3) * (1.f / 278.f) + 1e-5f);

    float* la = P.ln_a + (size_t)row * 288;
    #pragma unroll
    for (int i = 0; i < 4; ++i) {
        int k = lane + 64 * i;
        la[k] = (hv[i] - cm) * crstd * ldf(P.conf_ln_g, k, isb) + ldf(P.conf_ln_b, k, isb);
    }
    if (lane < 16) {
        int k = 260 + lane;
        la[k] = (ztl - cm) * crstd * ldf(P.conf_ln_g, k, isb) + ldf(P.conf_ln_b, k, isb);
    } else if (lane >= 18 && lane < 28) {
        la[260 + lane] = 0.f;   // 278..287
    }
    if (lane == 0) {
        float vals[6] = { yb, gmean, mx, gstd, ads, adsp };
        int idxs[6] = { 256, 257, 258, 259, 276, 277 };
        #pragma unroll
        for (int q = 0; q < 6; ++q) {
            int k = idxs[q];
            la[k] = (vals[q] - cm) * crstd * ldf(P.conf_ln_g, k, isb) + ldf(P.conf_ln_b, k, isb);
        }
        float* so = P.scal + (size_t)row * 32;
        so[4] = dsafe; so[5] = dspec;
    }
}

// ---------------- post_k: gamma + output ----------------
__global__ __launch_bounds__(256) void post_k(
    const float* __restrict__ ch, const float* __restrict__ scal,
    const void* __restrict__ conf_W2, const void* __restrict__ conf_b2,
    void* __restrict__ out, const int* __restrict__ flag)
{
    const int isb = *flag;
    const int wid = threadIdx.x >> 6;
    const int lane = threadIdx.x & 63;
    const int row = blockIdx.x * 4 + wid;

    float c0 = ch[(size_t)row * 128 + lane] * ldf(conf_W2, lane, isb);
    if (lane < 5) c0 += ch[(size_t)row * 128 + 64 + lane] * ldf(conf_W2, 64 + lane, isb);
    const float zlin = wred_sum(c0) + ldf(conf_b2, 0, isb);
    const float gamma = 1.f / (1.f + expf(-zlin));
    if (lane == 0) {
        const float* sc = scal + (size_t)row * 32;
        float v = sc[0] + sc[4] + gamma * sc[5];
        if (isb) ((u16*)out)[row] = f2b(v);
        else     ((float*)out)[row] = v;
    }
}

extern "C" void kernel_launch(void* const* d_in, const int* in_sizes, int n_in,
                              void* d_out, int out_size, void* d_ws, size_t ws_size,
                              hipStream_t stream) {
    (void)in_sizes; (void)n_in; (void)out_size; (void)ws_size;
    const void* x_num        = d_in[0];
    const void* basis_weight = d_in[1];
    const void* basis_bias   = d_in[2];
    const void* bp_min       = d_in[3];
    const void* bp_delta     = d_in[4];
    const void* proj_W       = d_in[5];
    const void* proj_b       = d_in[6];
    const void* gate_W1      = d_in[7];
    const void* gate_b1      = d_in[8];
    const void* gate_W2      = d_in[9];
    const void* gate_b2      = d_in[10];
    const void* bb_W1        = d_in[11];
    const void* bb_b1        = d_in[12];
    const void* bb_W2        = d_in[13];
    const void* bb_b2        = d_in[14];

    float* ws    = (float*)d_ws;
    int*   flag  = (int*)d_ws;
    float* bps   = ws + 16;                                // 4096
    float* x_in  = bps + 4096;                             // B*512
    float* gbuf  = x_in + (size_t)B_ROWS * D_FEAT;         // B*512 (later: ch = first B*128)
    float* hid   = gbuf + (size_t)B_ROWS * D_FEAT;         // B*256 (later: sh | sph)
    float* hbuf  = hid  + (size_t)B_ROWS * DT_;            // B*256
    float* ln_a  = hbuf + (size_t)B_ROWS * DT_;            // B*288 (safe LN, then conf LN)
    float* ln_b  = ln_a + (size_t)B_ROWS * 288;            // B*288 (spec LN)
    float* scal  = ln_b + (size_t)B_ROWS * 288;            // B*32
    float* sW1p  = scal + (size_t)B_ROWS * 32;             // 288*128
    float* cW1p  = sW1p + 288 * 128;                       // 288*128
    float* sb1p  = cW1p + 288 * 128;                       // 128
    float* cb1p  = sb1p + 128;                             // 128

    float* sh  = hid;                    // B*128
    float* sph = hid + (size_t)B_ROWS * 128;
    float* ch  = gbuf;                   // B*128

    const void* safe_W1 = d_in[19];
    const void* safe_b1 = d_in[20];
    const void* spec_W1 = d_in[29];
    const void* spec_b1 = d_in[30];
    const void* conf_W1 = d_in[35];
    const void* conf_b1 = d_in[36];

    detect_k<<<1, 64, 0, stream>>>(x_num, flag);
    prep_bps_k<<<1, 512, 0, stream>>>(bp_min, bp_delta, bps, flag);
    repack_k<<<144, 256, 0, stream>>>(spec_W1, spec_b1, conf_W1, conf_b1,
                                      sW1p, sb1p, cW1p, cb1p, flag);

    // x_in = x_num + 0.1*(flat @ proj_W + proj_b)
    gemm_k<1, 0, 0><<<dim3(B_ROWS / 64, 512 / 64), 256, 0, stream>>>(
        nullptr, nullptr, proj_W, proj_b, x_in,
        x_num, bps, basis_weight, basis_bias, B_ROWS, 512, 2048, 2048, flag);

    // gate hidden = relu(x_in @ gate_W1 + b1)
    gemm_k<0, 1, 0><<<dim3(B_ROWS / 64, 256 / 64), 256, 0, stream>>>(
        x_in, nullptr, gate_W1, gate_b1, hid,
        nullptr, nullptr, nullptr, nullptr, B_ROWS, 256, 512, 512, flag);

    // g = sigmoid(hidden @ gate_W2 + b2)
    gemm_k<0, 2, 0><<<dim3(B_ROWS / 64, 512 / 64), 256, 0, stream>>>(
        hid, nullptr, gate_W2, gate_b2, gbuf,
        nullptr, nullptr, nullptr, nullptr, B_ROWS, 512, 256, 256, flag);

    // bb hidden = relu((x_in * g) @ bb_W1 + b1)
    gemm_k<2, 1, 0><<<dim3(B_ROWS / 64, 256 / 64), 256, 0, stream>>>(
        x_in, gbuf, bb_W1, bb_b1, hid,
        nullptr, nullptr, nullptr, nullptr, B_ROWS, 256, 512, 512, flag);

    // h = relu(hidden @ bb_W2 + b2)
    gemm_k<0, 1, 0><<<dim3(B_ROWS / 64, 256 / 64), 256, 0, stream>>>(
        hid, nullptr, bb_W2, bb_b2, hbuf,
        nullptr, nullptr, nullptr, nullptr, B_ROWS, 256, 256, 256, flag);

    PreArgs pa;
    pa.x_in = x_in; pa.g = gbuf; pa.h = hbuf;
    pa.base_W    = d_in[15]; pa.base_b    = d_in[16];
    pa.safe_ln_g = d_in[17]; pa.safe_ln_b = d_in[18];
    pa.top_W1    = d_in[23]; pa.top_b1    = d_in[24];
    pa.top_W2    = d_in[25]; pa.top_b2    = d_in[26];
    pa.spec_ln_g = d_in[27]; pa.spec_ln_b = d_in[28];
    pa.ln_a = ln_a; pa.ln_b = ln_b; pa.scal = scal; pa.flag = flag;
    pre_k<<<B_ROWS / 4, 256, 0, stream>>>(pa);

    // safe hidden = relu(ln_a[:, :256] @ safe_W1 + b1)  [K=256, N=128]
    gemm_k<0, 1, 0><<<dim3(B_ROWS / 64, 2), 256, 0, stream>>>(
        ln_a, nullptr, safe_W1, safe_b1, sh,
        nullptr, nullptr, nullptr, nullptr, B_ROWS, 128, 256, 288, flag);

    // spec hidden = relu(ln_b @ spec_W1p + b1p)  [K=288 padded, N=128 padded]
    gemm_k<0, 1, 1><<<dim3(B_ROWS / 64, 2), 256, 0, stream>>>(
        ln_b, nullptr, sW1p, sb1p, sph,
        nullptr, nullptr, nullptr, nullptr, B_ROWS, 128, 288, 288, flag);

    MidArgs ma;
    ma.h = hbuf; ma.sh = sh; ma.sph = sph; ma.scal_in = scal;
    ma.safe_W2 = d_in[21]; ma.safe_b2 = d_in[22];
    ma.spec_W2 = d_in[31]; ma.spec_b2 = d_in[32];
    ma.conf_ln_g = d_in[33]; ma.conf_ln_b = d_in[34];
    ma.ln_a = ln_a; ma.scal = scal; ma.flag = flag;
    mid_k<<<B_ROWS / 4, 256, 0, stream>>>(ma);

    // conf hidden = relu(ln_a @ conf_W1p + b1p)  [K=288 padded, N=128 padded]
    gemm_k<0, 1, 1><<<dim3(B_ROWS / 64, 2), 256, 0, stream>>>(
        ln_a, nullptr, cW1p, cb1p, ch,
        nullptr, nullptr, nullptr, nullptr, B_ROWS, 128, 288, 288, flag);

    post_k<<<B_ROWS / 4, 256, 0, stream>>>(ch, scal, d_in[37], d_in[38], d_out, flag);
}

// Round 5
// 1538.665 us; speedup vs baseline: 2.1320x; 1.2442x over previous
//
#include <hip/hip_runtime.h>
#include <cstddef>

typedef unsigned short u16;
typedef unsigned int   u32;
typedef short bf16x8 __attribute__((ext_vector_type(8)));
typedef float f32x4 __attribute__((ext_vector_type(4)));

#define B_ROWS 16384
#define D_FEAT 512
#define NB_    8

static __device__ __forceinline__ float b2f(u16 h) {
    union { u32 u; float f; } v; v.u = ((u32)h) << 16; return v.f;
}
static __device__ __forceinline__ u16 f2b(float f) {
    union { float f; u32 u; } v; v.f = f;
    u32 r = (v.u + 0x7fffu + ((v.u >> 16) & 1u)) >> 16;
    return (u16)r;
}
static __device__ __forceinline__ float ldf(const void* p, size_t i, int isb) {
    return isb ? b2f(((const u16*)p)[i]) : ((const float*)p)[i];
}
static __device__ __forceinline__ u16 cvtb(const void* p, size_t i, int isb) {
    return isb ? ((const u16*)p)[i] : f2b(((const float*)p)[i]);
}
static __device__ __forceinline__ float wred_sum(float v) {
    #pragma unroll
    for (int off = 32; off > 0; off >>= 1) v += __shfl_xor(v, off);
    return v;
}
static __device__ __forceinline__ float wred_max(float v) {
    #pragma unroll
    for (int off = 32; off > 0; off >>= 1) v = fmaxf(v, __shfl_xor(v, off));
    return v;
}

// ---------------- dtype detector ----------------
__global__ void detect_k(const void* __restrict__ x, int* __restrict__ flag) {
    int lane = threadIdx.x & 63;
    u16 h = ((const u16*)x)[lane * 2];
    int e = (h >> 7) & 0xff;
    int plaus = (e >= 110 && e <= 132) ? 1 : 0;
    unsigned long long m = __ballot(plaus != 0);
    if (lane == 0) *flag = (__popcll(m) >= 32) ? 1 : 0;
}

// ---------------- breakpoints ----------------
__global__ void prep_bps_k(const void* __restrict__ bp_min, const void* __restrict__ bp_dr,
                           float* __restrict__ bps, const int* __restrict__ flag) {
    const int isb = *flag;
    int d = threadIdx.x;
    if (d < D_FEAT) {
        float bp = ldf(bp_min, d, isb);
        #pragma unroll
        for (int k = 0; k < NB_; ++k) {
            float x = ldf(bp_dr, d * NB_ + k, isb);
            bp += fmaxf(x, 0.f) + log1pf(expf(-fabsf(x)));
            bps[d * NB_ + k] = bp;
        }
    }
}

// Wbuf element offsets
#define WO_PROJ 0
#define WO_GW1  1048576
#define WO_GW2  1179648
#define WO_BW1  1310720
#define WO_BW2  1441792
#define WO_SW1  1507328
#define WO_SPW  1540096
#define WO_CFW  1576960
#define W_TOTAL 1613824

__global__ void repackW_k(const void* pW, const void* gW1, const void* gW2,
                          const void* bW1, const void* bW2, const void* sW1,
                          const void* spW, const void* cfW,
                          u16* __restrict__ dst, const int* __restrict__ flag) {
    const int isb = *flag;
    size_t t = (size_t)blockIdx.x * 256 + threadIdx.x;
    if (t >= W_TOTAL) return;
    if      (t < WO_GW1) dst[t] = cvtb(pW,  t - WO_PROJ, isb);
    else if (t < WO_GW2) dst[t] = cvtb(gW1, t - WO_GW1, isb);
    else if (t < WO_BW1) dst[t] = cvtb(gW2, t - WO_GW2, isb);
    else if (t < WO_BW2) dst[t] = cvtb(bW1, t - WO_BW1, isb);
    else if (t < WO_SW1) dst[t] = cvtb(bW2, t - WO_BW2, isb);
    else if (t < WO_SPW) dst[t] = cvtb(sW1, t - WO_SW1, isb);
    else if (t < WO_CFW) {
        size_t i = t - WO_SPW; int r = (int)(i >> 7), c = (int)(i & 127);
        dst[t] = (r < 272 && c < 68) ? cvtb(spW, (size_t)r * 68 + c, isb) : (u16)0;
    } else {
        size_t i = t - WO_CFW; int r = (int)(i >> 7), c = (int)(i & 127);
        dst[t] = (r < 278 && c < 69) ? cvtb(cfW, (size_t)r * 69 + c, isb) : (u16)0;
    }
}

__global__ void prep_bias_k(const void* pb, const void* g1, const void* g2,
                            const void* b1, const void* b2, const void* sb,
                            const void* spb, const void* cfb,
                            float* __restrict__ out, const int* __restrict__ flag) {
    const int isb = *flag;
    int t = blockIdx.x * 256 + threadIdx.x;
    if      (t < 512)  out[t] = ldf(pb, t, isb);
    else if (t < 768)  out[t] = ldf(g1, t - 512, isb);
    else if (t < 1280) out[t] = ldf(g2, t - 768, isb);
    else if (t < 1536) out[t] = ldf(b1, t - 1280, isb);
    else if (t < 1792) out[t] = ldf(b2, t - 1536, isb);
    else if (t < 1920) out[t] = ldf(sb, t - 1792, isb);
    else if (t < 2048) { int c = t - 1920; out[t] = (c < 68) ? ldf(spb, c, isb) : 0.f; }
    else if (t < 2176) { int c = t - 2048; out[t] = (c < 69) ? ldf(cfb, c, isb) : 0.f; }
}

// ---------------- embedding (half-batch): emb[local_b, d*4+e] bf16 ----------------
__global__ __launch_bounds__(256) void emb_k(
    const void* __restrict__ xnum, const void* __restrict__ bwt,
    const void* __restrict__ bbias, const float* __restrict__ bps,
    u16* __restrict__ emb, const int* __restrict__ flag, int rowoff)
{
    const int isb = *flag;
    size_t t = (size_t)blockIdx.x * 256 + threadIdx.x;
    int d = (int)(t & 511);
    float x = ldf(xnum, (size_t)rowoff * D_FEAT + t, isb);
    const float* bp = bps + d * 8;
    size_t wb = (size_t)d * 36;
    float e0 = ldf(bbias, d * 4 + 0, isb);
    float e1 = ldf(bbias, d * 4 + 1, isb);
    float e2 = ldf(bbias, d * 4 + 2, isb);
    float e3 = ldf(bbias, d * 4 + 3, isb);
    e0 = fmaf(x, ldf(bwt, wb + 0, isb), e0);
    e1 = fmaf(x, ldf(bwt, wb + 1, isb), e1);
    e2 = fmaf(x, ldf(bwt, wb + 2, isb), e2);
    e3 = fmaf(x, ldf(bwt, wb + 3, isb), e3);
    #pragma unroll
    for (int f = 1; f <= 8; ++f) {
        float bv = fmaxf(x - bp[f - 1], 0.f);
        e0 = fmaf(bv, ldf(bwt, wb + f * 4 + 0, isb), e0);
        e1 = fmaf(bv, ldf(bwt, wb + f * 4 + 1, isb), e1);
        e2 = fmaf(bv, ldf(bwt, wb + f * 4 + 2, isb), e2);
        e3 = fmaf(bv, ldf(bwt, wb + f * 4 + 3, isb), e3);
    }
    u16 o[4] = { f2b(e0), f2b(e1), f2b(e2), f2b(e3) };
    *(uint2*)&emb[t * 4] = *(const uint2*)o;
}

// ---------------- bf16 MFMA GEMM ----------------
// EMODE 0: residual -> bf16 (aux0 = xnum raw)   1: relu -> bf16
//       2: sigmoid -> f32 g (out0) + bf16 xg (aux1), aux0 = x_in bf16
//       3: relu -> f32
// A is indexed with LOCAL rows; out0/aux use rowoff+local row.
template<int EMODE>
__global__ __launch_bounds__(256) void mgemm_k(
    const u16* __restrict__ A, const u16* __restrict__ Bw,
    const float* __restrict__ bias,
    void* __restrict__ out0, const void* __restrict__ aux0, void* __restrict__ aux1,
    int N, int Kdim, int lda, int rowoff, const int* __restrict__ flagp)
{
    __shared__ __align__(16) u16 As[128][72];
    __shared__ __align__(16) u16 Bs[64][72];

    const int isb = (EMODE == 0) ? *flagp : 0;
    const int tid = threadIdx.x;
    const int row0 = blockIdx.x * 128, col0 = blockIdx.y * 64;
    const int w = tid >> 6, lane = tid & 63, q = lane >> 4, mr = lane & 15;

    f32x4 acc[2][4];
    #pragma unroll
    for (int a = 0; a < 2; ++a)
        #pragma unroll
        for (int b = 0; b < 4; ++b) acc[a][b] = (f32x4){0.f, 0.f, 0.f, 0.f};

    for (int kt = 0; kt < Kdim; kt += 64) {
        #pragma unroll
        for (int p = 0; p < 4; ++p) {
            int m = p * 32 + (tid >> 3);
            int kg = tid & 7;
            uint4 v = make_uint4(0u, 0u, 0u, 0u);
            if (kt + kg * 8 < Kdim)
                v = *(const uint4*)(A + (size_t)(row0 + m) * lda + kt + kg * 8);
            *(uint4*)&As[m][kg * 8] = v;
        }
        #pragma unroll
        for (int p = 0; p < 2; ++p) {
            int t = tid + p * 256;
            int n = t & 63, kg = t >> 6;
            union { u16 h[8]; uint4 v; } tb;
            int kbase = kt + kg * 8;
            if (kbase < Kdim) {
                #pragma unroll
                for (int j = 0; j < 8; ++j)
                    tb.h[j] = Bw[(size_t)(kbase + j) * N + col0 + n];
            } else {
                tb.v = make_uint4(0u, 0u, 0u, 0u);
            }
            *(uint4*)&Bs[n][kg * 8] = tb.v;
        }
        __syncthreads();
        #pragma unroll
        for (int ks = 0; ks < 2; ++ks) {
            bf16x8 af[2], bf[4];
            #pragma unroll
            for (int rs = 0; rs < 2; ++rs)
                af[rs] = *(const bf16x8*)&As[w * 32 + rs * 16 + mr][ks * 32 + q * 8];
            #pragma unroll
            for (int nt = 0; nt < 4; ++nt)
                bf[nt] = *(const bf16x8*)&Bs[nt * 16 + mr][ks * 32 + q * 8];
            #pragma unroll
            for (int rs = 0; rs < 2; ++rs)
                #pragma unroll
                for (int nt = 0; nt < 4; ++nt)
                    acc[rs][nt] = __builtin_amdgcn_mfma_f32_16x16x32_bf16(
                        af[rs], bf[nt], acc[rs][nt], 0, 0, 0);
        }
        __syncthreads();
    }

    #pragma unroll
    for (int rs = 0; rs < 2; ++rs) {
        #pragma unroll
        for (int i = 0; i < 4; ++i) {
            size_t gr = (size_t)rowoff + row0 + w * 32 + rs * 16 + q * 4 + i;
            #pragma unroll
            for (int nt = 0; nt < 4; ++nt) {
                int c = col0 + nt * 16 + mr;
                float z = acc[rs][nt][i] + bias[c];
                size_t idx = gr * (size_t)N + c;
                if (EMODE == 0) {
                    ((u16*)out0)[idx] = f2b(ldf(aux0, idx, isb) + 0.1f * z);
                } else if (EMODE == 1) {
                    ((u16*)out0)[idx] = f2b(fmaxf(z, 0.f));
                } else if (EMODE == 2) {
                    float gv = 1.f / (1.f + expf(-z));
                    ((float*)out0)[idx] = gv;
                    ((u16*)aux1)[idx] = f2b(b2f(((const u16*)aux0)[idx]) * gv);
                } else {
                    ((float*)out0)[idx] = fmaxf(z, 0.f);
                }
            }
        }
    }
}

// ---------------- pre_k ----------------
struct PreArgs {
    const u16 *x_in;
    const float *g, *h;
    const void *base_W, *base_b;
    const void *safe_ln_g, *safe_ln_b;
    const void *top_W1, *top_b1, *top_W2, *top_b2;
    const void *spec_ln_g, *spec_ln_b;
    u16 *ln_a, *ln_b;
    float *scal;
    const int *flag;
};

__global__ __launch_bounds__(256) void pre_k(PreArgs P) {
    __shared__ float zbs[4][16];
    const int isb = *P.flag;
    const int wid = threadIdx.x >> 6;
    const int lane = threadIdx.x & 63;
    const int row = blockIdx.x * 4 + wid;

    float hv[4], gv[8];
    #pragma unroll
    for (int i = 0; i < 4; ++i) hv[i] = P.h[(size_t)row * 256 + lane + 64 * i];
    #pragma unroll
    for (int j = 0; j < 8; ++j) gv[j] = P.g[(size_t)row * 512 + lane + 64 * j];
    const float hsum = hv[0] + hv[1] + hv[2] + hv[3];

    float pb = 0.f;
    #pragma unroll
    for (int i = 0; i < 4; ++i) pb = fmaf(hv[i], ldf(P.base_W, lane + 64 * i, isb), pb);
    const float yb = wred_sum(pb) + ldf(P.base_b, 0, isb);

    float s1 = 0.f, s2 = 0.f, mx = -1e30f;
    #pragma unroll
    for (int j = 0; j < 8; ++j) { s1 += gv[j]; s2 = fmaf(gv[j], gv[j], s2); mx = fmaxf(mx, gv[j]); }
    s1 = wred_sum(s1); s2 = wred_sum(s2); mx = wred_max(mx);
    const float gmean = s1 * (1.f / 512.f);
    const float gstd = sqrtf(fmaxf(s2 * (1.f / 512.f) - gmean * gmean, 0.f));

    // safe LN
    const float hm = wred_sum(hsum) * (1.f / 256.f);
    float pv = 0.f;
    #pragma unroll
    for (int i = 0; i < 4; ++i) { float d = hv[i] - hm; pv = fmaf(d, d, pv); }
    const float hrstd = rsqrtf(wred_sum(pv) * (1.f / 256.f) + 1e-5f);
    #pragma unroll
    for (int i = 0; i < 4; ++i) {
        int k = lane + 64 * i;
        P.ln_a[(size_t)row * 288 + k] =
            f2b((hv[i] - hm) * hrstd * ldf(P.safe_ln_g, k, isb) + ldf(P.safe_ln_b, k, isb));
    }

    // top-k
    float tg[8];
    #pragma unroll
    for (int j = 0; j < 8; ++j) tg[j] = gv[j];
    float myv = 0.f, sumtv = 0.f; int myi = 0;
    for (int r8 = 0; r8 < 8; ++r8) {
        float bv = -1e30f; int bi = 0x7fffffff;
        #pragma unroll
        for (int j = 0; j < 8; ++j) {
            int idx = lane + 64 * j;
            if (tg[j] > bv || (tg[j] == bv && idx < bi)) { bv = tg[j]; bi = idx; }
        }
        #pragma unroll
        for (int off = 32; off > 0; off >>= 1) {
            float ov = __shfl_xor(bv, off);
            int oi = __shfl_xor(bi, off);
            if (ov > bv || (ov == bv && oi < bi)) { bv = ov; bi = oi; }
        }
        sumtv += bv;
        if (lane == r8) { myv = bv; myi = bi; }
        if ((bi & 63) == lane) {
            int oj = bi >> 6;
            #pragma unroll
            for (int j = 0; j < 8; ++j) if (j == oj) tg[j] = -1e30f;
        }
    }

    float zt[16];
    #pragma unroll
    for (int t = 0; t < 16; ++t) zt[t] = 0.f;
    if (lane < 8) {
        float xi = b2f(P.x_in[(size_t)row * 512 + myi]);
        float xw = xi * (myv / (sumtv + 1e-6f));
        float th[16];
        #pragma unroll
        for (int s = 0; s < 16; ++s)
            th[s] = fmaxf(fmaf(xw, ldf(P.top_W1, s, isb), ldf(P.top_b1, s, isb)), 0.f);
        #pragma unroll
        for (int t = 0; t < 16; ++t) {
            float o = ldf(P.top_b2, t, isb);
            #pragma unroll
            for (int s = 0; s < 16; ++s) o = fmaf(th[s], ldf(P.top_W2, s * 16 + t, isb), o);
            zt[t] = o;
        }
    }
    #pragma unroll
    for (int t = 0; t < 16; ++t) {
        zt[t] += __shfl_xor(zt[t], 1);
        zt[t] += __shfl_xor(zt[t], 2);
        zt[t] += __shfl_xor(zt[t], 4);
    }
    if (lane == 0) {
        #pragma unroll
        for (int t = 0; t < 16; ++t) zbs[wid][t] = zt[t] * 0.125f;
    }
    __syncthreads();
    const float ztl = (lane < 16) ? zbs[wid][lane] : 0.f;

    // spec LN
    float ps = hsum + ((lane < 16) ? ztl : 0.f);
    const float sm = wred_sum(ps) * (1.f / 272.f);
    float pv2 = 0.f;
    #pragma unroll
    for (int i = 0; i < 4; ++i) { float d = hv[i] - sm; pv2 = fmaf(d, d, pv2); }
    if (lane < 16) { float d = ztl - sm; pv2 = fmaf(d, d, pv2); }
    const float srstd = rsqrtf(wred_sum(pv2) * (1.f / 272.f) + 1e-5f);
    #pragma unroll
    for (int i = 0; i < 4; ++i) {
        int k = lane + 64 * i;
        P.ln_b[(size_t)row * 288 + k] =
            f2b((hv[i] - sm) * srstd * ldf(P.spec_ln_g, k, isb) + ldf(P.spec_ln_b, k, isb));
    }
    if (lane < 16) {
        int k = 256 + lane;
        P.ln_b[(size_t)row * 288 + k] =
            f2b((ztl - sm) * srstd * ldf(P.spec_ln_g, k, isb) + ldf(P.spec_ln_b, k, isb));
    } else if (lane < 32) {
        P.ln_b[(size_t)row * 288 + 256 + lane] = 0;
    }

    if (lane == 0) {
        float* sc = P.scal + (size_t)row * 32;
        sc[0] = yb; sc[1] = gmean; sc[2] = mx; sc[3] = gstd;
        #pragma unroll
        for (int t = 0; t < 16; ++t) sc[8 + t] = zbs[wid][t];
    }
}

// ---------------- mid_k ----------------
struct MidArgs {
    const float *h, *scal_in;
    const u16 *sh, *sph;
    const void *safe_W2, *safe_b2, *spec_W2, *spec_b2;
    const void *conf_ln_g, *conf_ln_b;
    u16 *ln_c;
    float *scal;
    const int *flag;
};

__global__ __launch_bounds__(256) void mid_k(MidArgs P) {
    const int isb = *P.flag;
    const int wid = threadIdx.x >> 6;
    const int lane = threadIdx.x & 63;
    const int row = blockIdx.x * 4 + wid;

    float s0 = b2f(P.sh[(size_t)row * 128 + lane]);
    float s1 = b2f(P.sh[(size_t)row * 128 + 64 + lane]);
    float psafe = s0 * ldf(P.safe_W2, lane, isb) + s1 * ldf(P.safe_W2, 64 + lane, isb);
    const float dsafe = wred_sum(psafe) + ldf(P.safe_b2, 0, isb);

    float p0 = b2f(P.sph[(size_t)row * 128 + lane]) * ldf(P.spec_W2, lane, isb);
    if (lane < 4) p0 += b2f(P.sph[(size_t)row * 128 + 64 + lane]) * ldf(P.spec_W2, 64 + lane, isb);
    const float dspec = wred_sum(p0) + ldf(P.spec_b2, 0, isb);

    const float* sc = P.scal_in + (size_t)row * 32;
    const float yb = sc[0], gmean = sc[1], mx = sc[2], gstd = sc[3];
    const float ztl = (lane < 16) ? sc[8 + lane] : 0.f;

    float hv[4];
    #pragma unroll
    for (int i = 0; i < 4; ++i) hv[i] = P.h[(size_t)row * 256 + lane + 64 * i];
    const float hsum = hv[0] + hv[1] + hv[2] + hv[3];

    const float ads = fabsf(dsafe), adsp = fabsf(dspec);
    float pc = hsum + ((lane < 16) ? ztl : 0.f)
             + ((lane == 0) ? (yb + gmean + mx + gstd + ads + adsp) : 0.f);
    const float cm = wred_sum(pc) * (1.f / 278.f);
    float pv3 = 0.f;
    #pragma unroll
    for (int i = 0; i < 4; ++i) { float d = hv[i] - cm; pv3 = fmaf(d, d, pv3); }
    if (lane < 16) { float d = ztl - cm; pv3 = fmaf(d, d, pv3); }
    if (lane == 0) {
        float vals[6] = { yb, gmean, mx, gstd, ads, adsp };
        #pragma unroll
        for (int q = 0; q < 6; ++q) { float d = vals[q] - cm; pv3 = fmaf(d, d, pv3); }
    }
    const float crstd = rsqrtf(wred_sum(pv3) * (1.f / 278.f) + 1e-5f);

    u16* la = P.ln_c + (size_t)row * 288;
    #pragma unroll
    for (int i = 0; i < 4; ++i) {
        int k = lane + 64 * i;
        la[k] = f2b((hv[i] - cm) * crstd * ldf(P.conf_ln_g, k, isb) + ldf(P.conf_ln_b, k, isb));
    }
    if (lane < 16) {
        int k = 260 + lane;
        la[k] = f2b((ztl - cm) * crstd * ldf(P.conf_ln_g, k, isb) + ldf(P.conf_ln_b, k, isb));
    } else if (lane >= 18 && lane < 28) {
        la[260 + lane] = 0;
    }
    if (lane == 0) {
        float vals[6] = { yb, gmean, mx, gstd, ads, adsp };
        int idxs[6] = { 256, 257, 258, 259, 276, 277 };
        #pragma unroll
        for (int q = 0; q < 6; ++q) {
            int k = idxs[q];
            la[k] = f2b((vals[q] - cm) * crstd * ldf(P.conf_ln_g, k, isb) + ldf(P.conf_ln_b, k, isb));
        }
        float* so = P.scal + (size_t)row * 32;
        so[4] = dsafe; so[5] = dspec;
    }
}

// ---------------- post_k ----------------
__global__ __launch_bounds__(256) void post_k(
    const u16* __restrict__ ch, const float* __restrict__ scal,
    const void* __restrict__ conf_W2, const void* __restrict__ conf_b2,
    void* __restrict__ out, const int* __restrict__ flag)
{
    const int isb = *flag;
    const int wid = threadIdx.x >> 6;
    const int lane = threadIdx.x & 63;
    const int row = blockIdx.x * 4 + wid;

    float c0 = b2f(ch[(size_t)row * 128 + lane]) * ldf(conf_W2, lane, isb);
    if (lane < 5) c0 += b2f(ch[(size_t)row * 128 + 64 + lane]) * ldf(conf_W2, 64 + lane, isb);
    const float zlin = wred_sum(c0) + ldf(conf_b2, 0, isb);
    const float gamma = 1.f / (1.f + expf(-zlin));
    if (lane == 0) {
        const float* sc = scal + (size_t)row * 32;
        float v = sc[0] + sc[4] + gamma * sc[5];
        if (isb) ((u16*)out)[row] = f2b(v);
        else     ((float*)out)[row] = v;
    }
}

extern "C" void kernel_launch(void* const* d_in, const int* in_sizes, int n_in,
                              void* d_out, int out_size, void* d_ws, size_t ws_size,
                              hipStream_t stream) {
    (void)in_sizes; (void)n_in; (void)out_size; (void)ws_size;
    const void* x_num  = d_in[0];
    const void* bas_W  = d_in[1];
    const void* bas_b  = d_in[2];
    const void* bp_min = d_in[3];
    const void* bp_dr  = d_in[4];

    char* p = (char*)d_ws;
    auto alloc = [&](size_t bytes) { char* r = p; p += (bytes + 15) & ~(size_t)15; return r; };

    // total footprint ~133.3 MB (< 140.8 MB proven-safe in R3)
    int*   flag    = (int*)alloc(16);
    float* bps     = (float*)alloc(512 * 8 * 4);
    float* biasbuf = (float*)alloc(2176 * 4);
    u16*   Wbuf    = (u16*)alloc((size_t)W_TOTAL * 2);
    u16*   ebuf    = (u16*)alloc((size_t)(B_ROWS / 2) * 2048 * 2);  // 33.55 MB; later g f32
    u16*   x_in    = (u16*)alloc((size_t)B_ROWS * 512 * 2);
    u16*   hid1    = (u16*)alloc((size_t)B_ROWS * 256 * 2);         // later chh
    float* hbuf    = (float*)alloc((size_t)B_ROWS * 256 * 4);
    u16*   ln_a    = (u16*)alloc((size_t)B_ROWS * 288 * 2);
    u16*   ln_b    = (u16*)alloc((size_t)B_ROWS * 288 * 2);
    float* scal    = (float*)alloc((size_t)B_ROWS * 32 * 4);
    u16*   sh      = (u16*)alloc((size_t)B_ROWS * 128 * 2);
    u16*   sph     = (u16*)alloc((size_t)B_ROWS * 128 * 2);
    u16*   xg      = (u16*)alloc((size_t)B_ROWS * 512 * 2);
    u16*   hid2    = (u16*)alloc((size_t)B_ROWS * 256 * 2);

    float* g   = (float*)ebuf;   // 16384*512*4 = 33,554,432 B = ebuf size exactly
    u16*   chh = hid1;           // reuse after gate GEMMs done

    detect_k<<<1, 64, 0, stream>>>(x_num, flag);
    prep_bps_k<<<1, 512, 0, stream>>>(bp_min, bp_dr, bps, flag);
    repackW_k<<<(W_TOTAL + 255) / 256, 256, 0, stream>>>(
        d_in[5], d_in[7], d_in[9], d_in[11], d_in[13], d_in[19], d_in[29], d_in[35],
        Wbuf, flag);
    prep_bias_k<<<9, 256, 0, stream>>>(
        d_in[6], d_in[8], d_in[10], d_in[12], d_in[14], d_in[20], d_in[30], d_in[36],
        biasbuf, flag);

    // proj GEMM in two row-halves (ebuf holds one half's embedding at a time)
    const int HR = B_ROWS / 2;  // 8192
    for (int half = 0; half < 2; ++half) {
        int rowoff = half * HR;
        emb_k<<<(HR * D_FEAT) / 256, 256, 0, stream>>>(
            x_num, bas_W, bas_b, bps, ebuf, flag, rowoff);
        mgemm_k<0><<<dim3(HR / 128, 8), 256, 0, stream>>>(
            ebuf, Wbuf + WO_PROJ, biasbuf + 0, x_in, x_num, nullptr,
            512, 2048, 2048, rowoff, flag);
    }

    // hid1 = relu(x_in @ gate_W1 + b1)
    mgemm_k<1><<<dim3(B_ROWS / 128, 4), 256, 0, stream>>>(
        x_in, Wbuf + WO_GW1, biasbuf + 512, hid1, nullptr, nullptr, 256, 512, 512, 0, flag);
    // g = sigmoid(hid1 @ gate_W2 + b2) [f32, overwrites ebuf], xg = bf16(x_in * g)
    mgemm_k<2><<<dim3(B_ROWS / 128, 8), 256, 0, stream>>>(
        hid1, Wbuf + WO_GW2, biasbuf + 768, g, x_in, xg, 512, 256, 256, 0, flag);
    // hid2 = relu(xg @ bb_W1 + b1)
    mgemm_k<1><<<dim3(B_ROWS / 128, 4), 256, 0, stream>>>(
        xg, Wbuf + WO_BW1, biasbuf + 1280, hid2, nullptr, nullptr, 256, 512, 512, 0, flag);
    // h = relu(hid2 @ bb_W2 + b2) -> f32
    mgemm_k<3><<<dim3(B_ROWS / 128, 4), 256, 0, stream>>>(
        hid2, Wbuf + WO_BW2, biasbuf + 1536, hbuf, nullptr, nullptr, 256, 256, 256, 0, flag);

    {
        PreArgs pa;
        pa.x_in = x_in; pa.g = g; pa.h = hbuf;
        pa.base_W = d_in[15]; pa.base_b = d_in[16];
        pa.safe_ln_g = d_in[17]; pa.safe_ln_b = d_in[18];
        pa.top_W1 = d_in[23]; pa.top_b1 = d_in[24];
        pa.top_W2 = d_in[25]; pa.top_b2 = d_in[26];
        pa.spec_ln_g = d_in[27]; pa.spec_ln_b = d_in[28];
        pa.ln_a = ln_a; pa.ln_b = ln_b; pa.scal = scal; pa.flag = flag;
        pre_k<<<B_ROWS / 4, 256, 0, stream>>>(pa);
    }

    // sh = relu(ln_a[:, :256] @ safe_W1 + b1)
    mgemm_k<1><<<dim3(B_ROWS / 128, 2), 256, 0, stream>>>(
        ln_a, Wbuf + WO_SW1, biasbuf + 1792, sh, nullptr, nullptr, 128, 256, 288, 0, flag);
    // sph = relu(ln_b @ spec_W1p + b1p)
    mgemm_k<1><<<dim3(B_ROWS / 128, 2), 256, 0, stream>>>(
        ln_b, Wbuf + WO_SPW, biasbuf + 1920, sph, nullptr, nullptr, 128, 288, 288, 0, flag);

    {
        MidArgs ma;
        ma.h = hbuf; ma.scal_in = scal; ma.sh = sh; ma.sph = sph;
        ma.safe_W2 = d_in[21]; ma.safe_b2 = d_in[22];
        ma.spec_W2 = d_in[31]; ma.spec_b2 = d_in[32];
        ma.conf_ln_g = d_in[33]; ma.conf_ln_b = d_in[34];
        ma.ln_c = ln_a; ma.scal = scal; ma.flag = flag;
        mid_k<<<B_ROWS / 4, 256, 0, stream>>>(ma);
    }

    // chh = relu(ln_c @ conf_W1p + b1p)
    mgemm_k<1><<<dim3(B_ROWS / 128, 2), 256, 0, stream>>>(
        ln_a, Wbuf + WO_CFW, biasbuf + 2048, chh, nullptr, nullptr, 128, 288, 288, 0, flag);

    post_k<<<B_ROWS / 4, 256, 0, stream>>>(chh, scal, d_in[37], d_in[38], d_out, flag);
}

// Round 6
// 1156.822 us; speedup vs baseline: 2.8357x; 1.3301x over previous
//
#include <hip/hip_runtime.h>
#include <cstddef>

typedef unsigned short u16;
typedef unsigned int   u32;
typedef short bf16x8 __attribute__((ext_vector_type(8)));
typedef float f32x4 __attribute__((ext_vector_type(4)));

#define B_ROWS 16384
#define D_FEAT 512
#define NB_    8

static __device__ __forceinline__ float b2f(u16 h) {
    union { u32 u; float f; } v; v.u = ((u32)h) << 16; return v.f;
}
static __device__ __forceinline__ u16 f2b(float f) {
    union { float f; u32 u; } v; v.f = f;
    u32 r = (v.u + 0x7fffu + ((v.u >> 16) & 1u)) >> 16;
    return (u16)r;
}
static __device__ __forceinline__ float ldf(const void* p, size_t i, int isb) {
    return isb ? b2f(((const u16*)p)[i]) : ((const float*)p)[i];
}
static __device__ __forceinline__ u16 cvtb(const void* p, size_t i, int isb) {
    return isb ? ((const u16*)p)[i] : f2b(((const float*)p)[i]);
}
static __device__ __forceinline__ float wred_sum(float v) {
    #pragma unroll
    for (int off = 32; off > 0; off >>= 1) v += __shfl_xor(v, off);
    return v;
}
static __device__ __forceinline__ float wred_max(float v) {
    #pragma unroll
    for (int off = 32; off > 0; off >>= 1) v = fmaxf(v, __shfl_xor(v, off));
    return v;
}

// ---------------- dtype detector ----------------
__global__ void detect_k(const void* __restrict__ x, int* __restrict__ flag) {
    int lane = threadIdx.x & 63;
    u16 h = ((const u16*)x)[lane * 2];
    int e = (h >> 7) & 0xff;
    int plaus = (e >= 110 && e <= 132) ? 1 : 0;
    unsigned long long m = __ballot(plaus != 0);
    if (lane == 0) *flag = (__popcll(m) >= 32) ? 1 : 0;
}

// ---------------- breakpoints ----------------
__global__ void prep_bps_k(const void* __restrict__ bp_min, const void* __restrict__ bp_dr,
                           float* __restrict__ bps, const int* __restrict__ flag) {
    const int isb = *flag;
    int d = threadIdx.x;
    if (d < D_FEAT) {
        float bp = ldf(bp_min, d, isb);
        #pragma unroll
        for (int k = 0; k < NB_; ++k) {
            float x = ldf(bp_dr, d * NB_ + k, isb);
            bp += fmaxf(x, 0.f) + log1pf(expf(-fabsf(x)));
            bps[d * NB_ + k] = bp;
        }
    }
}

// Wbuf element offsets
#define WO_PROJ 0
#define WO_GW1  1048576
#define WO_GW2  1179648
#define WO_BW1  1310720
#define WO_BW2  1441792
#define WO_SW1  1507328
#define WO_SPW  1540096
#define WO_CFW  1576960
#define W_TOTAL 1613824

__global__ void repackW_k(const void* pW, const void* gW1, const void* gW2,
                          const void* bW1, const void* bW2, const void* sW1,
                          const void* spW, const void* cfW,
                          u16* __restrict__ dst, const int* __restrict__ flag) {
    const int isb = *flag;
    size_t t = (size_t)blockIdx.x * 256 + threadIdx.x;
    if (t >= W_TOTAL) return;
    if      (t < WO_GW1) dst[t] = cvtb(pW,  t - WO_PROJ, isb);
    else if (t < WO_GW2) dst[t] = cvtb(gW1, t - WO_GW1, isb);
    else if (t < WO_BW1) dst[t] = cvtb(gW2, t - WO_GW2, isb);
    else if (t < WO_BW2) dst[t] = cvtb(bW1, t - WO_BW1, isb);
    else if (t < WO_SW1) dst[t] = cvtb(bW2, t - WO_BW2, isb);
    else if (t < WO_SPW) dst[t] = cvtb(sW1, t - WO_SW1, isb);
    else if (t < WO_CFW) {
        size_t i = t - WO_SPW; int r = (int)(i >> 7), c = (int)(i & 127);
        dst[t] = (r < 272 && c < 68) ? cvtb(spW, (size_t)r * 68 + c, isb) : (u16)0;
    } else {
        size_t i = t - WO_CFW; int r = (int)(i >> 7), c = (int)(i & 127);
        dst[t] = (r < 278 && c < 69) ? cvtb(cfW, (size_t)r * 69 + c, isb) : (u16)0;
    }
}

__global__ void prep_bias_k(const void* pb, const void* g1, const void* g2,
                            const void* b1, const void* b2, const void* sb,
                            const void* spb, const void* cfb,
                            float* __restrict__ out, const int* __restrict__ flag) {
    const int isb = *flag;
    int t = blockIdx.x * 256 + threadIdx.x;
    if      (t < 512)  out[t] = ldf(pb, t, isb);
    else if (t < 768)  out[t] = ldf(g1, t - 512, isb);
    else if (t < 1280) out[t] = ldf(g2, t - 768, isb);
    else if (t < 1536) out[t] = ldf(b1, t - 1280, isb);
    else if (t < 1792) out[t] = ldf(b2, t - 1536, isb);
    else if (t < 1920) out[t] = ldf(sb, t - 1792, isb);
    else if (t < 2048) { int c = t - 1920; out[t] = (c < 68) ? ldf(spb, c, isb) : 0.f; }
    else if (t < 2176) { int c = t - 2048; out[t] = (c < 69) ? ldf(cfb, c, isb) : 0.f; }
}

// ---------------- embedding (half-batch) ----------------
__global__ __launch_bounds__(256) void emb_k(
    const void* __restrict__ xnum, const void* __restrict__ bwt,
    const void* __restrict__ bbias, const float* __restrict__ bps,
    u16* __restrict__ emb, const int* __restrict__ flag, int rowoff)
{
    const int isb = *flag;
    size_t t = (size_t)blockIdx.x * 256 + threadIdx.x;
    int d = (int)(t & 511);
    float x = ldf(xnum, (size_t)rowoff * D_FEAT + t, isb);
    const float* bp = bps + d * 8;
    size_t wb = (size_t)d * 36;
    float e0 = ldf(bbias, d * 4 + 0, isb);
    float e1 = ldf(bbias, d * 4 + 1, isb);
    float e2 = ldf(bbias, d * 4 + 2, isb);
    float e3 = ldf(bbias, d * 4 + 3, isb);
    e0 = fmaf(x, ldf(bwt, wb + 0, isb), e0);
    e1 = fmaf(x, ldf(bwt, wb + 1, isb), e1);
    e2 = fmaf(x, ldf(bwt, wb + 2, isb), e2);
    e3 = fmaf(x, ldf(bwt, wb + 3, isb), e3);
    #pragma unroll
    for (int f = 1; f <= 8; ++f) {
        float bv = fmaxf(x - bp[f - 1], 0.f);
        e0 = fmaf(bv, ldf(bwt, wb + f * 4 + 0, isb), e0);
        e1 = fmaf(bv, ldf(bwt, wb + f * 4 + 1, isb), e1);
        e2 = fmaf(bv, ldf(bwt, wb + f * 4 + 2, isb), e2);
        e3 = fmaf(bv, ldf(bwt, wb + f * 4 + 3, isb), e3);
    }
    u16 o[4] = { f2b(e0), f2b(e1), f2b(e2), f2b(e3) };
    *(uint2*)&emb[t * 4] = *(const uint2*)o;
}

// ---------------- bf16 MFMA GEMM (unchanged from R5) ----------------
template<int EMODE>
__global__ __launch_bounds__(256) void mgemm_k(
    const u16* __restrict__ A, const u16* __restrict__ Bw,
    const float* __restrict__ bias,
    void* __restrict__ out0, const void* __restrict__ aux0, void* __restrict__ aux1,
    int N, int Kdim, int lda, int rowoff, const int* __restrict__ flagp)
{
    __shared__ __align__(16) u16 As[128][72];
    __shared__ __align__(16) u16 Bs[64][72];

    const int isb = (EMODE == 0) ? *flagp : 0;
    const int tid = threadIdx.x;
    const int row0 = blockIdx.x * 128, col0 = blockIdx.y * 64;
    const int w = tid >> 6, lane = tid & 63, q = lane >> 4, mr = lane & 15;

    f32x4 acc[2][4];
    #pragma unroll
    for (int a = 0; a < 2; ++a)
        #pragma unroll
        for (int b = 0; b < 4; ++b) acc[a][b] = (f32x4){0.f, 0.f, 0.f, 0.f};

    for (int kt = 0; kt < Kdim; kt += 64) {
        #pragma unroll
        for (int p = 0; p < 4; ++p) {
            int m = p * 32 + (tid >> 3);
            int kg = tid & 7;
            uint4 v = make_uint4(0u, 0u, 0u, 0u);
            if (kt + kg * 8 < Kdim)
                v = *(const uint4*)(A + (size_t)(row0 + m) * lda + kt + kg * 8);
            *(uint4*)&As[m][kg * 8] = v;
        }
        #pragma unroll
        for (int p = 0; p < 2; ++p) {
            int t = tid + p * 256;
            int n = t & 63, kg = t >> 6;
            union { u16 h[8]; uint4 v; } tb;
            int kbase = kt + kg * 8;
            if (kbase < Kdim) {
                #pragma unroll
                for (int j = 0; j < 8; ++j)
                    tb.h[j] = Bw[(size_t)(kbase + j) * N + col0 + n];
            } else {
                tb.v = make_uint4(0u, 0u, 0u, 0u);
            }
            *(uint4*)&Bs[n][kg * 8] = tb.v;
        }
        __syncthreads();
        #pragma unroll
        for (int ks = 0; ks < 2; ++ks) {
            bf16x8 af[2], bf[4];
            #pragma unroll
            for (int rs = 0; rs < 2; ++rs)
                af[rs] = *(const bf16x8*)&As[w * 32 + rs * 16 + mr][ks * 32 + q * 8];
            #pragma unroll
            for (int nt = 0; nt < 4; ++nt)
                bf[nt] = *(const bf16x8*)&Bs[nt * 16 + mr][ks * 32 + q * 8];
            #pragma unroll
            for (int rs = 0; rs < 2; ++rs)
                #pragma unroll
                for (int nt = 0; nt < 4; ++nt)
                    acc[rs][nt] = __builtin_amdgcn_mfma_f32_16x16x32_bf16(
                        af[rs], bf[nt], acc[rs][nt], 0, 0, 0);
        }
        __syncthreads();
    }

    #pragma unroll
    for (int rs = 0; rs < 2; ++rs) {
        #pragma unroll
        for (int i = 0; i < 4; ++i) {
            size_t gr = (size_t)rowoff + row0 + w * 32 + rs * 16 + q * 4 + i;
            #pragma unroll
            for (int nt = 0; nt < 4; ++nt) {
                int c = col0 + nt * 16 + mr;
                float z = acc[rs][nt][i] + bias[c];
                size_t idx = gr * (size_t)N + c;
                if (EMODE == 0) {
                    ((u16*)out0)[idx] = f2b(ldf(aux0, idx, isb) + 0.1f * z);
                } else if (EMODE == 1) {
                    ((u16*)out0)[idx] = f2b(fmaxf(z, 0.f));
                } else if (EMODE == 2) {
                    float gv = 1.f / (1.f + expf(-z));
                    ((float*)out0)[idx] = gv;
                    ((u16*)aux1)[idx] = f2b(b2f(((const u16*)aux0)[idx]) * gv);
                } else {
                    ((float*)out0)[idx] = fmaxf(z, 0.f);
                }
            }
        }
    }
}

// ---------------- pre_k: LDS-cached weights, parallel token MLP ----------------
struct PreArgs {
    const u16 *x_in;
    const float *g, *h;
    const void *base_W, *base_b;
    const void *safe_ln_g, *safe_ln_b;
    const void *top_W1, *top_b1, *top_W2, *top_b2;
    const void *spec_ln_g, *spec_ln_b;
    u16 *ln_a, *ln_b;
    float *scal;
    const int *flag;
};

__global__ __launch_bounds__(256, 4) void pre_k(PreArgs P) {
    __shared__ float w_base[256], w_slg[256], w_slb[256], w_t2[256];
    __shared__ float w_plg[272], w_plb[272];
    __shared__ float w_t1[16], w_tb1[16], w_tb2[16];
    const int isb = *P.flag;
    const int tid = threadIdx.x;
    const int wid = tid >> 6;
    const int lane = tid & 63;
    const int row = blockIdx.x * 4 + wid;

    // cooperative weight staging (once per block)
    w_base[tid] = ldf(P.base_W, tid, isb);
    w_slg[tid]  = ldf(P.safe_ln_g, tid, isb);
    w_slb[tid]  = ldf(P.safe_ln_b, tid, isb);
    w_t2[tid]   = ldf(P.top_W2, tid, isb);
    if (tid < 272) {
        w_plg[tid] = ldf(P.spec_ln_g, tid, isb);
        w_plb[tid] = ldf(P.spec_ln_b, tid, isb);
    }
    if (tid < 16) {
        w_t1[tid]  = ldf(P.top_W1, tid, isb);
        w_tb1[tid] = ldf(P.top_b1, tid, isb);
        w_tb2[tid] = ldf(P.top_b2, tid, isb);
    }
    __syncthreads();

    float hv[4], gv[8];
    #pragma unroll
    for (int i = 0; i < 4; ++i) hv[i] = P.h[(size_t)row * 256 + lane + 64 * i];
    #pragma unroll
    for (int j = 0; j < 8; ++j) gv[j] = P.g[(size_t)row * 512 + lane + 64 * j];
    const float hsum = hv[0] + hv[1] + hv[2] + hv[3];

    float pb = 0.f;
    #pragma unroll
    for (int i = 0; i < 4; ++i) pb = fmaf(hv[i], w_base[lane + 64 * i], pb);
    const float yb = wred_sum(pb) + ldf(P.base_b, 0, isb);

    float s1 = 0.f, s2 = 0.f, mx = -1e30f;
    #pragma unroll
    for (int j = 0; j < 8; ++j) { s1 += gv[j]; s2 = fmaf(gv[j], gv[j], s2); mx = fmaxf(mx, gv[j]); }
    s1 = wred_sum(s1); s2 = wred_sum(s2); mx = wred_max(mx);
    const float gmean = s1 * (1.f / 512.f);
    const float gstd = sqrtf(fmaxf(s2 * (1.f / 512.f) - gmean * gmean, 0.f));

    // safe LN -> ln_a
    const float hm = wred_sum(hsum) * (1.f / 256.f);
    float pv = 0.f;
    #pragma unroll
    for (int i = 0; i < 4; ++i) { float d = hv[i] - hm; pv = fmaf(d, d, pv); }
    const float hrstd = rsqrtf(wred_sum(pv) * (1.f / 256.f) + 1e-5f);
    #pragma unroll
    for (int i = 0; i < 4; ++i) {
        int k = lane + 64 * i;
        P.ln_a[(size_t)row * 288 + k] = f2b((hv[i] - hm) * hrstd * w_slg[k] + w_slb[k]);
    }

    // top-k (K=8), desc value / asc index ties
    float tg[8];
    #pragma unroll
    for (int j = 0; j < 8; ++j) tg[j] = gv[j];
    float myv = 0.f, sumtv = 0.f; int myi = 0;
    for (int r8 = 0; r8 < 8; ++r8) {
        float bv = -1e30f; int bi = 0x7fffffff;
        #pragma unroll
        for (int j = 0; j < 8; ++j) {
            int idx = lane + 64 * j;
            if (tg[j] > bv || (tg[j] == bv && idx < bi)) { bv = tg[j]; bi = idx; }
        }
        #pragma unroll
        for (int off = 32; off > 0; off >>= 1) {
            float ov = __shfl_xor(bv, off);
            int oi = __shfl_xor(bi, off);
            if (ov > bv || (ov == bv && oi < bi)) { bv = ov; bi = oi; }
        }
        sumtv += bv;
        if (lane == r8) { myv = bv; myi = bi; }
        if ((bi & 63) == lane) {
            int oj = bi >> 6;
            #pragma unroll
            for (int j = 0; j < 8; ++j) if (j == oj) tg[j] = -1e30f;
        }
    }

    // token MLP: th per token (lanes 0..7), then S[s]=sum_k th_k[s], z[t]=(1/8)(b2[t]+S.W2[:,t])
    float th[16];
    #pragma unroll
    for (int s = 0; s < 16; ++s) th[s] = 0.f;
    if (lane < 8) {
        float xi = b2f(P.x_in[(size_t)row * 512 + myi]);
        float xw = xi * (myv / (sumtv + 1e-6f));
        #pragma unroll
        for (int s = 0; s < 16; ++s)
            th[s] = fmaxf(fmaf(xw, w_t1[s], w_tb1[s]), 0.f);
    }
    #pragma unroll
    for (int s = 0; s < 16; ++s) {
        th[s] += __shfl_xor(th[s], 1);
        th[s] += __shfl_xor(th[s], 2);
        th[s] += __shfl_xor(th[s], 4);
    }
    // all lanes compute z_top[lane&15] from lane-0 broadcast of S
    const int tt = lane & 15;
    float zacc = w_tb2[tt];
    #pragma unroll
    for (int s = 0; s < 16; ++s)
        zacc = fmaf(__shfl(th[s], 0), w_t2[s * 16 + tt], zacc);
    const float ztl = zacc * 0.125f;   // z_top[lane&15], valid on every lane

    // spec LN over [h(256), z_top(16)]
    float ps = hsum + ((lane < 16) ? ztl : 0.f);
    const float sm = wred_sum(ps) * (1.f / 272.f);
    float pv2 = 0.f;
    #pragma unroll
    for (int i = 0; i < 4; ++i) { float d = hv[i] - sm; pv2 = fmaf(d, d, pv2); }
    if (lane < 16) { float d = ztl - sm; pv2 = fmaf(d, d, pv2); }
    const float srstd = rsqrtf(wred_sum(pv2) * (1.f / 272.f) + 1e-5f);
    #pragma unroll
    for (int i = 0; i < 4; ++i) {
        int k = lane + 64 * i;
        P.ln_b[(size_t)row * 288 + k] = f2b((hv[i] - sm) * srstd * w_plg[k] + w_plb[k]);
    }
    if (lane < 16) {
        int k = 256 + lane;
        P.ln_b[(size_t)row * 288 + k] = f2b((ztl - sm) * srstd * w_plg[k] + w_plb[k]);
    } else if (lane < 32) {
        P.ln_b[(size_t)row * 288 + 256 + lane] = 0;
    }

    float* sc = P.scal + (size_t)row * 32;
    if (lane < 16) sc[8 + lane] = ztl;
    if (lane == 0) { sc[0] = yb; sc[1] = gmean; sc[2] = mx; sc[3] = gstd; }
}

// ---------------- mid_k: LDS-cached weights ----------------
struct MidArgs {
    const float *h, *scal_in;
    const u16 *sh, *sph;
    const void *safe_W2, *safe_b2, *spec_W2, *spec_b2;
    const void *conf_ln_g, *conf_ln_b;
    u16 *ln_c;
    float *scal;
    const int *flag;
};

__global__ __launch_bounds__(256, 4) void mid_k(MidArgs P) {
    __shared__ float w_clg[278], w_clb[278], w_sw2[128], w_spw2[68];
    const int isb = *P.flag;
    const int tid = threadIdx.x;
    const int wid = tid >> 6;
    const int lane = tid & 63;
    const int row = blockIdx.x * 4 + wid;

    if (tid < 278) { w_clg[tid] = ldf(P.conf_ln_g, tid, isb); w_clb[tid] = ldf(P.conf_ln_b, tid, isb); }
    if (tid < 128) w_sw2[tid]  = ldf(P.safe_W2, tid, isb);
    if (tid < 68)  w_spw2[tid] = ldf(P.spec_W2, tid, isb);
    __syncthreads();

    float s0 = b2f(P.sh[(size_t)row * 128 + lane]);
    float s1 = b2f(P.sh[(size_t)row * 128 + 64 + lane]);
    float psafe = s0 * w_sw2[lane] + s1 * w_sw2[64 + lane];
    const float dsafe = wred_sum(psafe) + ldf(P.safe_b2, 0, isb);

    float p0 = b2f(P.sph[(size_t)row * 128 + lane]) * ((lane < 68) ? w_spw2[lane] : 0.f);
    if (lane < 4) p0 += b2f(P.sph[(size_t)row * 128 + 64 + lane]) * w_spw2[64 + lane];
    const float dspec = wred_sum(p0) + ldf(P.spec_b2, 0, isb);

    const float* sc = P.scal_in + (size_t)row * 32;
    const float yb = sc[0], gmean = sc[1], mx = sc[2], gstd = sc[3];
    const float ztl = (lane < 16) ? sc[8 + lane] : 0.f;

    float hv[4];
    #pragma unroll
    for (int i = 0; i < 4; ++i) hv[i] = P.h[(size_t)row * 256 + lane + 64 * i];
    const float hsum = hv[0] + hv[1] + hv[2] + hv[3];

    const float ads = fabsf(dsafe), adsp = fabsf(dspec);
    float pc = hsum + ((lane < 16) ? ztl : 0.f)
             + ((lane == 0) ? (yb + gmean + mx + gstd + ads + adsp) : 0.f);
    const float cm = wred_sum(pc) * (1.f / 278.f);
    float pv3 = 0.f;
    #pragma unroll
    for (int i = 0; i < 4; ++i) { float d = hv[i] - cm; pv3 = fmaf(d, d, pv3); }
    if (lane < 16) { float d = ztl - cm; pv3 = fmaf(d, d, pv3); }
    if (lane == 0) {
        float vals[6] = { yb, gmean, mx, gstd, ads, adsp };
        #pragma unroll
        for (int q = 0; q < 6; ++q) { float d = vals[q] - cm; pv3 = fmaf(d, d, pv3); }
    }
    const float crstd = rsqrtf(wred_sum(pv3) * (1.f / 278.f) + 1e-5f);

    u16* la = P.ln_c + (size_t)row * 288;
    #pragma unroll
    for (int i = 0; i < 4; ++i) {
        int k = lane + 64 * i;
        la[k] = f2b((hv[i] - cm) * crstd * w_clg[k] + w_clb[k]);
    }
    if (lane < 16) {
        int k = 260 + lane;
        la[k] = f2b((ztl - cm) * crstd * w_clg[k] + w_clb[k]);
    } else if (lane >= 18 && lane < 28) {
        la[260 + lane] = 0;
    }
    if (lane == 0) {
        float vals[6] = { yb, gmean, mx, gstd, ads, adsp };
        int idxs[6] = { 256, 257, 258, 259, 276, 277 };
        #pragma unroll
        for (int q = 0; q < 6; ++q) {
            int k = idxs[q];
            la[k] = f2b((vals[q] - cm) * crstd * w_clg[k] + w_clb[k]);
        }
        float* so = P.scal + (size_t)row * 32;
        so[4] = dsafe; so[5] = dspec;
    }
}

// ---------------- post_k ----------------
__global__ __launch_bounds__(256, 4) void post_k(
    const u16* __restrict__ ch, const float* __restrict__ scal,
    const void* __restrict__ conf_W2, const void* __restrict__ conf_b2,
    void* __restrict__ out, const int* __restrict__ flag)
{
    __shared__ float w_cw2[69];
    const int isb = *flag;
    const int tid = threadIdx.x;
    const int wid = tid >> 6;
    const int lane = tid & 63;
    const int row = blockIdx.x * 4 + wid;

    if (tid < 69) w_cw2[tid] = ldf(conf_W2, tid, isb);
    __syncthreads();

    float c0 = b2f(ch[(size_t)row * 128 + lane]) * ((lane < 69) ? w_cw2[lane] : 0.f);
    if (lane < 5) c0 += b2f(ch[(size_t)row * 128 + 64 + lane]) * w_cw2[64 + lane];
    const float zlin = wred_sum(c0) + ldf(conf_b2, 0, isb);
    const float gamma = 1.f / (1.f + expf(-zlin));
    if (lane == 0) {
        const float* sc = scal + (size_t)row * 32;
        float v = sc[0] + sc[4] + gamma * sc[5];
        if (isb) ((u16*)out)[row] = f2b(v);
        else     ((float*)out)[row] = v;
    }
}

extern "C" void kernel_launch(void* const* d_in, const int* in_sizes, int n_in,
                              void* d_out, int out_size, void* d_ws, size_t ws_size,
                              hipStream_t stream) {
    (void)in_sizes; (void)n_in; (void)out_size; (void)ws_size;
    const void* x_num  = d_in[0];
    const void* bas_W  = d_in[1];
    const void* bas_b  = d_in[2];
    const void* bp_min = d_in[3];
    const void* bp_dr  = d_in[4];

    char* p = (char*)d_ws;
    auto alloc = [&](size_t bytes) { char* r = p; p += (bytes + 15) & ~(size_t)15; return r; };

    // total footprint ~133.3 MB (< 140.8 MB proven-safe in R3)
    int*   flag    = (int*)alloc(16);
    float* bps     = (float*)alloc(512 * 8 * 4);
    float* biasbuf = (float*)alloc(2176 * 4);
    u16*   Wbuf    = (u16*)alloc((size_t)W_TOTAL * 2);
    u16*   ebuf    = (u16*)alloc((size_t)(B_ROWS / 2) * 2048 * 2);  // 33.55 MB; later g f32
    u16*   x_in    = (u16*)alloc((size_t)B_ROWS * 512 * 2);
    u16*   hid1    = (u16*)alloc((size_t)B_ROWS * 256 * 2);         // later chh
    float* hbuf    = (float*)alloc((size_t)B_ROWS * 256 * 4);
    u16*   ln_a    = (u16*)alloc((size_t)B_ROWS * 288 * 2);
    u16*   ln_b    = (u16*)alloc((size_t)B_ROWS * 288 * 2);
    float* scal    = (float*)alloc((size_t)B_ROWS * 32 * 4);
    u16*   sh      = (u16*)alloc((size_t)B_ROWS * 128 * 2);
    u16*   sph     = (u16*)alloc((size_t)B_ROWS * 128 * 2);
    u16*   xg      = (u16*)alloc((size_t)B_ROWS * 512 * 2);
    u16*   hid2    = (u16*)alloc((size_t)B_ROWS * 256 * 2);

    float* g   = (float*)ebuf;   // 16384*512*4 = ebuf size exactly
    u16*   chh = hid1;           // reuse after gate GEMMs done

    detect_k<<<1, 64, 0, stream>>>(x_num, flag);
    prep_bps_k<<<1, 512, 0, stream>>>(bp_min, bp_dr, bps, flag);
    repackW_k<<<(W_TOTAL + 255) / 256, 256, 0, stream>>>(
        d_in[5], d_in[7], d_in[9], d_in[11], d_in[13], d_in[19], d_in[29], d_in[35],
        Wbuf, flag);
    prep_bias_k<<<9, 256, 0, stream>>>(
        d_in[6], d_in[8], d_in[10], d_in[12], d_in[14], d_in[20], d_in[30], d_in[36],
        biasbuf, flag);

    const int HR = B_ROWS / 2;  // 8192
    for (int half = 0; half < 2; ++half) {
        int rowoff = half * HR;
        emb_k<<<(HR * D_FEAT) / 256, 256, 0, stream>>>(
            x_num, bas_W, bas_b, bps, ebuf, flag, rowoff);
        mgemm_k<0><<<dim3(HR / 128, 8), 256, 0, stream>>>(
            ebuf, Wbuf + WO_PROJ, biasbuf + 0, x_in, x_num, nullptr,
            512, 2048, 2048, rowoff, flag);
    }

    mgemm_k<1><<<dim3(B_ROWS / 128, 4), 256, 0, stream>>>(
        x_in, Wbuf + WO_GW1, biasbuf + 512, hid1, nullptr, nullptr, 256, 512, 512, 0, flag);
    mgemm_k<2><<<dim3(B_ROWS / 128, 8), 256, 0, stream>>>(
        hid1, Wbuf + WO_GW2, biasbuf + 768, g, x_in, xg, 512, 256, 256, 0, flag);
    mgemm_k<1><<<dim3(B_ROWS / 128, 4), 256, 0, stream>>>(
        xg, Wbuf + WO_BW1, biasbuf + 1280, hid2, nullptr, nullptr, 256, 512, 512, 0, flag);
    mgemm_k<3><<<dim3(B_ROWS / 128, 4), 256, 0, stream>>>(
        hid2, Wbuf + WO_BW2, biasbuf + 1536, hbuf, nullptr, nullptr, 256, 256, 256, 0, flag);

    {
        PreArgs pa;
        pa.x_in = x_in; pa.g = g; pa.h = hbuf;
        pa.base_W = d_in[15]; pa.base_b = d_in[16];
        pa.safe_ln_g = d_in[17]; pa.safe_ln_b = d_in[18];
        pa.top_W1 = d_in[23]; pa.top_b1 = d_in[24];
        pa.top_W2 = d_in[25]; pa.top_b2 = d_in[26];
        pa.spec_ln_g = d_in[27]; pa.spec_ln_b = d_in[28];
        pa.ln_a = ln_a; pa.ln_b = ln_b; pa.scal = scal; pa.flag = flag;
        pre_k<<<B_ROWS / 4, 256, 0, stream>>>(pa);
    }

    mgemm_k<1><<<dim3(B_ROWS / 128, 2), 256, 0, stream>>>(
        ln_a, Wbuf + WO_SW1, biasbuf + 1792, sh, nullptr, nullptr, 128, 256, 288, 0, flag);
    mgemm_k<1><<<dim3(B_ROWS / 128, 2), 256, 0, stream>>>(
        ln_b, Wbuf + WO_SPW, biasbuf + 1920, sph, nullptr, nullptr, 128, 288, 288, 0, flag);

    {
        MidArgs ma;
        ma.h = hbuf; ma.scal_in = scal; ma.sh = sh; ma.sph = sph;
        ma.safe_W2 = d_in[21]; ma.safe_b2 = d_in[22];
        ma.spec_W2 = d_in[31]; ma.spec_b2 = d_in[32];
        ma.conf_ln_g = d_in[33]; ma.conf_ln_b = d_in[34];
        ma.ln_c = ln_a; ma.scal = scal; ma.flag = flag;
        mid_k<<<B_ROWS / 4, 256, 0, stream>>>(ma);
    }

    mgemm_k<1><<<dim3(B_ROWS / 128, 2), 256, 0, stream>>>(
        ln_a, Wbuf + WO_CFW, biasbuf + 2048, chh, nullptr, nullptr, 128, 288, 288, 0, flag);

    post_k<<<B_ROWS / 4, 256, 0, stream>>>(chh, scal, d_in[37], d_in[38], d_out, flag);
}

// Round 7
// 543.724 us; speedup vs baseline: 6.0333x; 2.1276x over previous
//
#include <hip/hip_runtime.h>
#include <cstddef>

typedef unsigned short u16;
typedef unsigned int   u32;
typedef short bf16x8 __attribute__((ext_vector_type(8)));
typedef float f32x4 __attribute__((ext_vector_type(4)));

#define B_ROWS 16384
#define D_FEAT 512
#define NB_    8

static __device__ __forceinline__ float b2f(u16 h) {
    union { u32 u; float f; } v; v.u = ((u32)h) << 16; return v.f;
}
static __device__ __forceinline__ u16 f2b(float f) {
    union { float f; u32 u; } v; v.f = f;
    u32 r = (v.u + 0x7fffu + ((v.u >> 16) & 1u)) >> 16;
    return (u16)r;
}
static __device__ __forceinline__ float ldf(const void* p, size_t i, int isb) {
    return isb ? b2f(((const u16*)p)[i]) : ((const float*)p)[i];
}
static __device__ __forceinline__ u16 cvtb(const void* p, size_t i, int isb) {
    return isb ? ((const u16*)p)[i] : f2b(((const float*)p)[i]);
}
static __device__ __forceinline__ float wred_sum(float v) {
    #pragma unroll
    for (int off = 32; off > 0; off >>= 1) v += __shfl_xor(v, off);
    return v;
}
static __device__ __forceinline__ float wred_max(float v) {
    #pragma unroll
    for (int off = 32; off > 0; off >>= 1) v = fmaxf(v, __shfl_xor(v, off));
    return v;
}

// ---------------- dtype detector ----------------
__global__ void detect_k(const void* __restrict__ x, int* __restrict__ flag) {
    int lane = threadIdx.x & 63;
    u16 h = ((const u16*)x)[lane * 2];
    int e = (h >> 7) & 0xff;
    int plaus = (e >= 110 && e <= 132) ? 1 : 0;
    unsigned long long m = __ballot(plaus != 0);
    if (lane == 0) *flag = (__popcll(m) >= 32) ? 1 : 0;
}

// ---------------- breakpoints (TRANSPOSED: bpsT[k][d]) ----------------
__global__ void prep_bps_k(const void* __restrict__ bp_min, const void* __restrict__ bp_dr,
                           float* __restrict__ bpsT, const int* __restrict__ flag) {
    const int isb = *flag;
    int d = threadIdx.x;
    if (d < D_FEAT) {
        float bp = ldf(bp_min, d, isb);
        #pragma unroll
        for (int k = 0; k < NB_; ++k) {
            float x = ldf(bp_dr, d * NB_ + k, isb);
            bp += fmaxf(x, 0.f) + log1pf(expf(-fabsf(x)));
            bpsT[k * 512 + d] = bp;
        }
    }
}

// ---------------- embedding tables TRANSPOSED f32: bwT[j][d] (j=f*4+e), bbT[e][d] ----
__global__ void prep_embT_k(const void* __restrict__ bwt, const void* __restrict__ bbias,
                            float* __restrict__ bwT, float* __restrict__ bbT,
                            const int* __restrict__ flag) {
    const int isb = *flag;
    int t = blockIdx.x * 256 + threadIdx.x;
    if (t < 512 * 36) {
        int d = t / 36, j = t % 36;
        bwT[j * 512 + d] = ldf(bwt, t, isb);
    }
    if (t < 2048) {
        int d = t >> 2, e = t & 3;
        bbT[e * 512 + d] = ldf(bbias, t, isb);
    }
}

// Wbuf element offsets
#define WO_PROJ 0
#define WO_GW1  1048576
#define WO_GW2  1179648
#define WO_BW1  1310720
#define WO_BW2  1441792
#define WO_SW1  1507328
#define WO_SPW  1540096
#define WO_CFW  1576960
#define W_TOTAL 1613824

__global__ void repackW_k(const void* pW, const void* gW1, const void* gW2,
                          const void* bW1, const void* bW2, const void* sW1,
                          const void* spW, const void* cfW,
                          u16* __restrict__ dst, const int* __restrict__ flag) {
    const int isb = *flag;
    size_t t = (size_t)blockIdx.x * 256 + threadIdx.x;
    if (t >= W_TOTAL) return;
    if      (t < WO_GW1) dst[t] = cvtb(pW,  t - WO_PROJ, isb);
    else if (t < WO_GW2) dst[t] = cvtb(gW1, t - WO_GW1, isb);
    else if (t < WO_BW1) dst[t] = cvtb(gW2, t - WO_GW2, isb);
    else if (t < WO_BW2) dst[t] = cvtb(bW1, t - WO_BW1, isb);
    else if (t < WO_SW1) dst[t] = cvtb(bW2, t - WO_BW2, isb);
    else if (t < WO_SPW) dst[t] = cvtb(sW1, t - WO_SW1, isb);
    else if (t < WO_CFW) {
        size_t i = t - WO_SPW; int r = (int)(i >> 7), c = (int)(i & 127);
        dst[t] = (r < 272 && c < 68) ? cvtb(spW, (size_t)r * 68 + c, isb) : (u16)0;
    } else {
        size_t i = t - WO_CFW; int r = (int)(i >> 7), c = (int)(i & 127);
        dst[t] = (r < 278 && c < 69) ? cvtb(cfW, (size_t)r * 69 + c, isb) : (u16)0;
    }
}

__global__ void prep_bias_k(const void* pb, const void* g1, const void* g2,
                            const void* b1, const void* b2, const void* sb,
                            const void* spb, const void* cfb,
                            float* __restrict__ out, const int* __restrict__ flag) {
    const int isb = *flag;
    int t = blockIdx.x * 256 + threadIdx.x;
    if      (t < 512)  out[t] = ldf(pb, t, isb);
    else if (t < 768)  out[t] = ldf(g1, t - 512, isb);
    else if (t < 1280) out[t] = ldf(g2, t - 768, isb);
    else if (t < 1536) out[t] = ldf(b1, t - 1280, isb);
    else if (t < 1792) out[t] = ldf(b2, t - 1536, isb);
    else if (t < 1920) out[t] = ldf(sb, t - 1792, isb);
    else if (t < 2048) { int c = t - 1920; out[t] = (c < 68) ? ldf(spb, c, isb) : 0.f; }
    else if (t < 2176) { int c = t - 2048; out[t] = (c < 69) ? ldf(cfb, c, isb) : 0.f; }
}

// ---------------- embedding (half-batch), coalesced transposed tables ----------------
__global__ __launch_bounds__(256) void emb_k(
    const void* __restrict__ xnum, const float* __restrict__ bwT,
    const float* __restrict__ bbT, const float* __restrict__ bpsT,
    u16* __restrict__ emb, const int* __restrict__ flag, int rowoff)
{
    const int isb = *flag;
    size_t t = (size_t)blockIdx.x * 256 + threadIdx.x;
    int d = (int)(t & 511);
    float x = ldf(xnum, (size_t)rowoff * D_FEAT + t, isb);
    float e0 = bbT[d], e1 = bbT[512 + d], e2 = bbT[1024 + d], e3 = bbT[1536 + d];
    e0 = fmaf(x, bwT[d], e0);
    e1 = fmaf(x, bwT[512 + d], e1);
    e2 = fmaf(x, bwT[1024 + d], e2);
    e3 = fmaf(x, bwT[1536 + d], e3);
    #pragma unroll
    for (int f = 1; f <= 8; ++f) {
        float bv = fmaxf(x - bpsT[(f - 1) * 512 + d], 0.f);
        e0 = fmaf(bv, bwT[(f * 4 + 0) * 512 + d], e0);
        e1 = fmaf(bv, bwT[(f * 4 + 1) * 512 + d], e1);
        e2 = fmaf(bv, bwT[(f * 4 + 2) * 512 + d], e2);
        e3 = fmaf(bv, bwT[(f * 4 + 3) * 512 + d], e3);
    }
    u16 o[4] = { f2b(e0), f2b(e1), f2b(e2), f2b(e3) };
    *(uint2*)&emb[t * 4] = *(const uint2*)o;
}

// ---------------- bf16 MFMA GEMM (unchanged) ----------------
template<int EMODE>
__global__ __launch_bounds__(256) void mgemm_k(
    const u16* __restrict__ A, const u16* __restrict__ Bw,
    const float* __restrict__ bias,
    void* __restrict__ out0, const void* __restrict__ aux0, void* __restrict__ aux1,
    int N, int Kdim, int lda, int rowoff, const int* __restrict__ flagp)
{
    __shared__ __align__(16) u16 As[128][72];
    __shared__ __align__(16) u16 Bs[64][72];

    const int isb = (EMODE == 0) ? *flagp : 0;
    const int tid = threadIdx.x;
    const int row0 = blockIdx.x * 128, col0 = blockIdx.y * 64;
    const int w = tid >> 6, lane = tid & 63, q = lane >> 4, mr = lane & 15;

    f32x4 acc[2][4];
    #pragma unroll
    for (int a = 0; a < 2; ++a)
        #pragma unroll
        for (int b = 0; b < 4; ++b) acc[a][b] = (f32x4){0.f, 0.f, 0.f, 0.f};

    for (int kt = 0; kt < Kdim; kt += 64) {
        #pragma unroll
        for (int p = 0; p < 4; ++p) {
            int m = p * 32 + (tid >> 3);
            int kg = tid & 7;
            uint4 v = make_uint4(0u, 0u, 0u, 0u);
            if (kt + kg * 8 < Kdim)
                v = *(const uint4*)(A + (size_t)(row0 + m) * lda + kt + kg * 8);
            *(uint4*)&As[m][kg * 8] = v;
        }
        #pragma unroll
        for (int p = 0; p < 2; ++p) {
            int t = tid + p * 256;
            int n = t & 63, kg = t >> 6;
            union { u16 h[8]; uint4 v; } tb;
            int kbase = kt + kg * 8;
            if (kbase < Kdim) {
                #pragma unroll
                for (int j = 0; j < 8; ++j)
                    tb.h[j] = Bw[(size_t)(kbase + j) * N + col0 + n];
            } else {
                tb.v = make_uint4(0u, 0u, 0u, 0u);
            }
            *(uint4*)&Bs[n][kg * 8] = tb.v;
        }
        __syncthreads();
        #pragma unroll
        for (int ks = 0; ks < 2; ++ks) {
            bf16x8 af[2], bf[4];
            #pragma unroll
            for (int rs = 0; rs < 2; ++rs)
                af[rs] = *(const bf16x8*)&As[w * 32 + rs * 16 + mr][ks * 32 + q * 8];
            #pragma unroll
            for (int nt = 0; nt < 4; ++nt)
                bf[nt] = *(const bf16x8*)&Bs[nt * 16 + mr][ks * 32 + q * 8];
            #pragma unroll
            for (int rs = 0; rs < 2; ++rs)
                #pragma unroll
                for (int nt = 0; nt < 4; ++nt)
                    acc[rs][nt] = __builtin_amdgcn_mfma_f32_16x16x32_bf16(
                        af[rs], bf[nt], acc[rs][nt], 0, 0, 0);
        }
        __syncthreads();
    }

    #pragma unroll
    for (int rs = 0; rs < 2; ++rs) {
        #pragma unroll
        for (int i = 0; i < 4; ++i) {
            size_t gr = (size_t)rowoff + row0 + w * 32 + rs * 16 + q * 4 + i;
            #pragma unroll
            for (int nt = 0; nt < 4; ++nt) {
                int c = col0 + nt * 16 + mr;
                float z = acc[rs][nt][i] + bias[c];
                size_t idx = gr * (size_t)N + c;
                if (EMODE == 0) {
                    ((u16*)out0)[idx] = f2b(ldf(aux0, idx, isb) + 0.1f * z);
                } else if (EMODE == 1) {
                    ((u16*)out0)[idx] = f2b(fmaxf(z, 0.f));
                } else if (EMODE == 2) {
                    float gv = 1.f / (1.f + expf(-z));
                    ((float*)out0)[idx] = gv;
                    ((u16*)aux1)[idx] = f2b(b2f(((const u16*)aux0)[idx]) * gv);
                } else {
                    ((float*)out0)[idx] = fmaxf(z, 0.f);
                }
            }
        }
    }
}

// ---------------- pre_k (unchanged from R6) ----------------
struct PreArgs {
    const u16 *x_in;
    const float *g, *h;
    const void *base_W, *base_b;
    const void *safe_ln_g, *safe_ln_b;
    const void *top_W1, *top_b1, *top_W2, *top_b2;
    const void *spec_ln_g, *spec_ln_b;
    u16 *ln_a, *ln_b;
    float *scal;
    const int *flag;
};

__global__ __launch_bounds__(256, 4) void pre_k(PreArgs P) {
    __shared__ float w_base[256], w_slg[256], w_slb[256], w_t2[256];
    __shared__ float w_plg[272], w_plb[272];
    __shared__ float w_t1[16], w_tb1[16], w_tb2[16];
    const int isb = *P.flag;
    const int tid = threadIdx.x;
    const int wid = tid >> 6;
    const int lane = tid & 63;
    const int row = blockIdx.x * 4 + wid;

    w_base[tid] = ldf(P.base_W, tid, isb);
    w_slg[tid]  = ldf(P.safe_ln_g, tid, isb);
    w_slb[tid]  = ldf(P.safe_ln_b, tid, isb);
    w_t2[tid]   = ldf(P.top_W2, tid, isb);
    if (tid < 272) {
        w_plg[tid] = ldf(P.spec_ln_g, tid, isb);
        w_plb[tid] = ldf(P.spec_ln_b, tid, isb);
    }
    if (tid < 16) {
        w_t1[tid]  = ldf(P.top_W1, tid, isb);
        w_tb1[tid] = ldf(P.top_b1, tid, isb);
        w_tb2[tid] = ldf(P.top_b2, tid, isb);
    }
    __syncthreads();

    float hv[4], gv[8];
    #pragma unroll
    for (int i = 0; i < 4; ++i) hv[i] = P.h[(size_t)row * 256 + lane + 64 * i];
    #pragma unroll
    for (int j = 0; j < 8; ++j) gv[j] = P.g[(size_t)row * 512 + lane + 64 * j];
    const float hsum = hv[0] + hv[1] + hv[2] + hv[3];

    float pb = 0.f;
    #pragma unroll
    for (int i = 0; i < 4; ++i) pb = fmaf(hv[i], w_base[lane + 64 * i], pb);
    const float yb = wred_sum(pb) + ldf(P.base_b, 0, isb);

    float s1 = 0.f, s2 = 0.f, mx = -1e30f;
    #pragma unroll
    for (int j = 0; j < 8; ++j) { s1 += gv[j]; s2 = fmaf(gv[j], gv[j], s2); mx = fmaxf(mx, gv[j]); }
    s1 = wred_sum(s1); s2 = wred_sum(s2); mx = wred_max(mx);
    const float gmean = s1 * (1.f / 512.f);
    const float gstd = sqrtf(fmaxf(s2 * (1.f / 512.f) - gmean * gmean, 0.f));

    const float hm = wred_sum(hsum) * (1.f / 256.f);
    float pv = 0.f;
    #pragma unroll
    for (int i = 0; i < 4; ++i) { float d = hv[i] - hm; pv = fmaf(d, d, pv); }
    const float hrstd = rsqrtf(wred_sum(pv) * (1.f / 256.f) + 1e-5f);
    #pragma unroll
    for (int i = 0; i < 4; ++i) {
        int k = lane + 64 * i;
        P.ln_a[(size_t)row * 288 + k] = f2b((hv[i] - hm) * hrstd * w_slg[k] + w_slb[k]);
    }

    float tg[8];
    #pragma unroll
    for (int j = 0; j < 8; ++j) tg[j] = gv[j];
    float myv = 0.f, sumtv = 0.f; int myi = 0;
    for (int r8 = 0; r8 < 8; ++r8) {
        float bv = -1e30f; int bi = 0x7fffffff;
        #pragma unroll
        for (int j = 0; j < 8; ++j) {
            int idx = lane + 64 * j;
            if (tg[j] > bv || (tg[j] == bv && idx < bi)) { bv = tg[j]; bi = idx; }
        }
        #pragma unroll
        for (int off = 32; off > 0; off >>= 1) {
            float ov = __shfl_xor(bv, off);
            int oi = __shfl_xor(bi, off);
            if (ov > bv || (ov == bv && oi < bi)) { bv = ov; bi = oi; }
        }
        sumtv += bv;
        if (lane == r8) { myv = bv; myi = bi; }
        if ((bi & 63) == lane) {
            int oj = bi >> 6;
            #pragma unroll
            for (int j = 0; j < 8; ++j) if (j == oj) tg[j] = -1e30f;
        }
    }

    float th[16];
    #pragma unroll
    for (int s = 0; s < 16; ++s) th[s] = 0.f;
    if (lane < 8) {
        float xi = b2f(P.x_in[(size_t)row * 512 + myi]);
        float xw = xi * (myv / (sumtv + 1e-6f));
        #pragma unroll
        for (int s = 0; s < 16; ++s)
            th[s] = fmaxf(fmaf(xw, w_t1[s], w_tb1[s]), 0.f);
    }
    #pragma unroll
    for (int s = 0; s < 16; ++s) {
        th[s] += __shfl_xor(th[s], 1);
        th[s] += __shfl_xor(th[s], 2);
        th[s] += __shfl_xor(th[s], 4);
    }
    const int tt = lane & 15;
    float zacc = w_tb2[tt];
    #pragma unroll
    for (int s = 0; s < 16; ++s)
        zacc = fmaf(__shfl(th[s], 0), w_t2[s * 16 + tt], zacc);
    const float ztl = zacc * 0.125f;

    float ps = hsum + ((lane < 16) ? ztl : 0.f);
    const float sm = wred_sum(ps) * (1.f / 272.f);
    float pv2 = 0.f;
    #pragma unroll
    for (int i = 0; i < 4; ++i) { float d = hv[i] - sm; pv2 = fmaf(d, d, pv2); }
    if (lane < 16) { float d = ztl - sm; pv2 = fmaf(d, d, pv2); }
    const float srstd = rsqrtf(wred_sum(pv2) * (1.f / 272.f) + 1e-5f);
    #pragma unroll
    for (int i = 0; i < 4; ++i) {
        int k = lane + 64 * i;
        P.ln_b[(size_t)row * 288 + k] = f2b((hv[i] - sm) * srstd * w_plg[k] + w_plb[k]);
    }
    if (lane < 16) {
        int k = 256 + lane;
        P.ln_b[(size_t)row * 288 + k] = f2b((ztl - sm) * srstd * w_plg[k] + w_plb[k]);
    } else if (lane < 32) {
        P.ln_b[(size_t)row * 288 + 256 + lane] = 0;
    }

    float* sc = P.scal + (size_t)row * 32;
    if (lane < 16) sc[8 + lane] = ztl;
    if (lane == 0) { sc[0] = yb; sc[1] = gmean; sc[2] = mx; sc[3] = gstd; }
}

// ---------------- mid_k (unchanged from R6) ----------------
struct MidArgs {
    const float *h, *scal_in;
    const u16 *sh, *sph;
    const void *safe_W2, *safe_b2, *spec_W2, *spec_b2;
    const void *conf_ln_g, *conf_ln_b;
    u16 *ln_c;
    float *scal;
    const int *flag;
};

__global__ __launch_bounds__(256, 4) void mid_k(MidArgs P) {
    __shared__ float w_clg[278], w_clb[278], w_sw2[128], w_spw2[68];
    const int isb = *P.flag;
    const int tid = threadIdx.x;
    const int wid = tid >> 6;
    const int lane = tid & 63;
    const int row = blockIdx.x * 4 + wid;

    if (tid < 278) { w_clg[tid] = ldf(P.conf_ln_g, tid, isb); w_clb[tid] = ldf(P.conf_ln_b, tid, isb); }
    if (tid < 128) w_sw2[tid]  = ldf(P.safe_W2, tid, isb);
    if (tid < 68)  w_spw2[tid] = ldf(P.spec_W2, tid, isb);
    __syncthreads();

    float s0 = b2f(P.sh[(size_t)row * 128 + lane]);
    float s1 = b2f(P.sh[(size_t)row * 128 + 64 + lane]);
    float psafe = s0 * w_sw2[lane] + s1 * w_sw2[64 + lane];
    const float dsafe = wred_sum(psafe) + ldf(P.safe_b2, 0, isb);

    float p0 = b2f(P.sph[(size_t)row * 128 + lane]) * ((lane < 68) ? w_spw2[lane] : 0.f);
    if (lane < 4) p0 += b2f(P.sph[(size_t)row * 128 + 64 + lane]) * w_spw2[64 + lane];
    const float dspec = wred_sum(p0) + ldf(P.spec_b2, 0, isb);

    const float* sc = P.scal_in + (size_t)row * 32;
    const float yb = sc[0], gmean = sc[1], mx = sc[2], gstd = sc[3];
    const float ztl = (lane < 16) ? sc[8 + lane] : 0.f;

    float hv[4];
    #pragma unroll
    for (int i = 0; i < 4; ++i) hv[i] = P.h[(size_t)row * 256 + lane + 64 * i];
    const float hsum = hv[0] + hv[1] + hv[2] + hv[3];

    const float ads = fabsf(dsafe), adsp = fabsf(dspec);
    float pc = hsum + ((lane < 16) ? ztl : 0.f)
             + ((lane == 0) ? (yb + gmean + mx + gstd + ads + adsp) : 0.f);
    const float cm = wred_sum(pc) * (1.f / 278.f);
    float pv3 = 0.f;
    #pragma unroll
    for (int i = 0; i < 4; ++i) { float d = hv[i] - cm; pv3 = fmaf(d, d, pv3); }
    if (lane < 16) { float d = ztl - cm; pv3 = fmaf(d, d, pv3); }
    if (lane == 0) {
        float vals[6] = { yb, gmean, mx, gstd, ads, adsp };
        #pragma unroll
        for (int q = 0; q < 6; ++q) { float d = vals[q] - cm; pv3 = fmaf(d, d, pv3); }
    }
    const float crstd = rsqrtf(wred_sum(pv3) * (1.f / 278.f) + 1e-5f);

    u16* la = P.ln_c + (size_t)row * 288;
    #pragma unroll
    for (int i = 0; i < 4; ++i) {
        int k = lane + 64 * i;
        la[k] = f2b((hv[i] - cm) * crstd * w_clg[k] + w_clb[k]);
    }
    if (lane < 16) {
        int k = 260 + lane;
        la[k] = f2b((ztl - cm) * crstd * w_clg[k] + w_clb[k]);
    } else if (lane >= 18 && lane < 28) {
        la[260 + lane] = 0;
    }
    if (lane == 0) {
        float vals[6] = { yb, gmean, mx, gstd, ads, adsp };
        int idxs[6] = { 256, 257, 258, 259, 276, 277 };
        #pragma unroll
        for (int q = 0; q < 6; ++q) {
            int k = idxs[q];
            la[k] = f2b((vals[q] - cm) * crstd * w_clg[k] + w_clb[k]);
        }
        float* so = P.scal + (size_t)row * 32;
        so[4] = dsafe; so[5] = dspec;
    }
}

// ---------------- post_k (unchanged from R6) ----------------
__global__ __launch_bounds__(256, 4) void post_k(
    const u16* __restrict__ ch, const float* __restrict__ scal,
    const void* __restrict__ conf_W2, const void* __restrict__ conf_b2,
    void* __restrict__ out, const int* __restrict__ flag)
{
    __shared__ float w_cw2[69];
    const int isb = *flag;
    const int tid = threadIdx.x;
    const int wid = tid >> 6;
    const int lane = tid & 63;
    const int row = blockIdx.x * 4 + wid;

    if (tid < 69) w_cw2[tid] = ldf(conf_W2, tid, isb);
    __syncthreads();

    float c0 = b2f(ch[(size_t)row * 128 + lane]) * ((lane < 69) ? w_cw2[lane] : 0.f);
    if (lane < 5) c0 += b2f(ch[(size_t)row * 128 + 64 + lane]) * w_cw2[64 + lane];
    const float zlin = wred_sum(c0) + ldf(conf_b2, 0, isb);
    const float gamma = 1.f / (1.f + expf(-zlin));
    if (lane == 0) {
        const float* sc = scal + (size_t)row * 32;
        float v = sc[0] + sc[4] + gamma * sc[5];
        if (isb) ((u16*)out)[row] = f2b(v);
        else     ((float*)out)[row] = v;
    }
}

extern "C" void kernel_launch(void* const* d_in, const int* in_sizes, int n_in,
                              void* d_out, int out_size, void* d_ws, size_t ws_size,
                              hipStream_t stream) {
    (void)in_sizes; (void)n_in; (void)out_size; (void)ws_size;
    const void* x_num  = d_in[0];
    const void* bas_W  = d_in[1];
    const void* bas_b  = d_in[2];
    const void* bp_min = d_in[3];
    const void* bp_dr  = d_in[4];

    char* p = (char*)d_ws;
    auto alloc = [&](size_t bytes) { char* r = p; p += (bytes + 15) & ~(size_t)15; return r; };

    // total footprint ~133.4 MB (< 140.8 MB proven-safe in R3)
    int*   flag    = (int*)alloc(16);
    float* bpsT    = (float*)alloc(8 * 512 * 4);
    float* bwT     = (float*)alloc(36 * 512 * 4);
    float* bbT     = (float*)alloc(4 * 512 * 4);
    float* biasbuf = (float*)alloc(2176 * 4);
    u16*   Wbuf    = (u16*)alloc((size_t)W_TOTAL * 2);
    u16*   ebuf    = (u16*)alloc((size_t)(B_ROWS / 2) * 2048 * 2);  // 33.55 MB; later g f32
    u16*   x_in    = (u16*)alloc((size_t)B_ROWS * 512 * 2);
    u16*   hid1    = (u16*)alloc((size_t)B_ROWS * 256 * 2);         // later chh
    float* hbuf    = (float*)alloc((size_t)B_ROWS * 256 * 4);
    u16*   ln_a    = (u16*)alloc((size_t)B_ROWS * 288 * 2);
    u16*   ln_b    = (u16*)alloc((size_t)B_ROWS * 288 * 2);
    float* scal    = (float*)alloc((size_t)B_ROWS * 32 * 4);
    u16*   sh      = (u16*)alloc((size_t)B_ROWS * 128 * 2);
    u16*   sph     = (u16*)alloc((size_t)B_ROWS * 128 * 2);
    u16*   xg      = (u16*)alloc((size_t)B_ROWS * 512 * 2);
    u16*   hid2    = (u16*)alloc((size_t)B_ROWS * 256 * 2);

    float* g   = (float*)ebuf;   // 16384*512*4 = ebuf size exactly
    u16*   chh = hid1;           // reuse after gate GEMMs done

    detect_k<<<1, 64, 0, stream>>>(x_num, flag);
    prep_bps_k<<<1, 512, 0, stream>>>(bp_min, bp_dr, bpsT, flag);
    prep_embT_k<<<72, 256, 0, stream>>>(bas_W, bas_b, bwT, bbT, flag);
    repackW_k<<<(W_TOTAL + 255) / 256, 256, 0, stream>>>(
        d_in[5], d_in[7], d_in[9], d_in[11], d_in[13], d_in[19], d_in[29], d_in[35],
        Wbuf, flag);
    prep_bias_k<<<9, 256, 0, stream>>>(
        d_in[6], d_in[8], d_in[10], d_in[12], d_in[14], d_in[20], d_in[30], d_in[36],
        biasbuf, flag);

    const int HR = B_ROWS / 2;  // 8192
    for (int half = 0; half < 2; ++half) {
        int rowoff = half * HR;
        emb_k<<<(HR * D_FEAT) / 256, 256, 0, stream>>>(
            x_num, bwT, bbT, bpsT, ebuf, flag, rowoff);
        mgemm_k<0><<<dim3(HR / 128, 8), 256, 0, stream>>>(
            ebuf, Wbuf + WO_PROJ, biasbuf + 0, x_in, x_num, nullptr,
            512, 2048, 2048, rowoff, flag);
    }

    mgemm_k<1><<<dim3(B_ROWS / 128, 4), 256, 0, stream>>>(
        x_in, Wbuf + WO_GW1, biasbuf + 512, hid1, nullptr, nullptr, 256, 512, 512, 0, flag);
    mgemm_k<2><<<dim3(B_ROWS / 128, 8), 256, 0, stream>>>(
        hid1, Wbuf + WO_GW2, biasbuf + 768, g, x_in, xg, 512, 256, 256, 0, flag);
    mgemm_k<1><<<dim3(B_ROWS / 128, 4), 256, 0, stream>>>(
        xg, Wbuf + WO_BW1, biasbuf + 1280, hid2, nullptr, nullptr, 256, 512, 512, 0, flag);
    mgemm_k<3><<<dim3(B_ROWS / 128, 4), 256, 0, stream>>>(
        hid2, Wbuf + WO_BW2, biasbuf + 1536, hbuf, nullptr, nullptr, 256, 256, 256, 0, flag);

    {
        PreArgs pa;
        pa.x_in = x_in; pa.g = g; pa.h = hbuf;
        pa.base_W = d_in[15]; pa.base_b = d_in[16];
        pa.safe_ln_g = d_in[17]; pa.safe_ln_b = d_in[18];
        pa.top_W1 = d_in[23]; pa.top_b1 = d_in[24];
        pa.top_W2 = d_in[25]; pa.top_b2 = d_in[26];
        pa.spec_ln_g = d_in[27]; pa.spec_ln_b = d_in[28];
        pa.ln_a = ln_a; pa.ln_b = ln_b; pa.scal = scal; pa.flag = flag;
        pre_k<<<B_ROWS / 4, 256, 0, stream>>>(pa);
    }

    mgemm_k<1><<<dim3(B_ROWS / 128, 2), 256, 0, stream>>>(
        ln_a, Wbuf + WO_SW1, biasbuf + 1792, sh, nullptr, nullptr, 128, 256, 288, 0, flag);
    mgemm_k<1><<<dim3(B_ROWS / 128, 2), 256, 0, stream>>>(
        ln_b, Wbuf + WO_SPW, biasbuf + 1920, sph, nullptr, nullptr, 128, 288, 288, 0, flag);

    {
        MidArgs ma;
        ma.h = hbuf; ma.scal_in = scal; ma.sh = sh; ma.sph = sph;
        ma.safe_W2 = d_in[21]; ma.safe_b2 = d_in[22];
        ma.spec_W2 = d_in[31]; ma.spec_b2 = d_in[32];
        ma.conf_ln_g = d_in[33]; ma.conf_ln_b = d_in[34];
        ma.ln_c = ln_a; ma.scal = scal; ma.flag = flag;
        mid_k<<<B_ROWS / 4, 256, 0, stream>>>(ma);
    }

    mgemm_k<1><<<dim3(B_ROWS / 128, 2), 256, 0, stream>>>(
        ln_a, Wbuf + WO_CFW, biasbuf + 2048, chh, nullptr, nullptr, 128, 288, 288, 0, flag);

    post_k<<<B_ROWS / 4, 256, 0, stream>>>(chh, scal, d_in[37], d_in[38], d_out, flag);
}